// Round 6
// baseline (1240.958 us; speedup 1.0000x reference)
//
#include <hip/hip_runtime.h>
#include <cstdint>
#include <cstddef>

#define TK 10

typedef unsigned short u16;
typedef __attribute__((ext_vector_type(8))) short short8;
typedef __attribute__((ext_vector_type(4))) float f32x4;

__device__ __forceinline__ float4 ld4(const float* p){ return *(const float4*)p; }

// fp32 -> bf16 round-to-nearest-even, and back
__device__ __forceinline__ u16 bfr(float x){
  unsigned u = __float_as_uint(x);
  return (u16)((u + 0x7FFFu + ((u >> 16) & 1u)) >> 16);
}
__device__ __forceinline__ float b2f(u16 h){
  unsigned u = ((unsigned)h) << 16;
  return __uint_as_float(u);
}

// ---------------------------------------------------------------------------
// wt_transpose: one launch packs all weights W[K,N] fp32 -> Wt (transposed,
// zero-padded) as SPLIT bf16: hi at [0, Np*Kp), lo at [Np*Kp, 2*Np*Kp).
// ---------------------------------------------------------------------------
struct TD { const float* W; u16* Wt; int K, Kp, N, Np; };
struct TDs { TD d[10]; };

__global__ __launch_bounds__(256) void wt_transpose_kernel(TDs ds)
{
  TD d = ds.d[blockIdx.y];
  const size_t loOff = (size_t)d.Np * d.Kp;
  const int tilesN = d.Np >> 6;
  const int tiles  = (d.Kp >> 6) * tilesN;
  const int tid = blockIdx.x;
  if (tid >= tiles) return;
  const int k0 = (tid / tilesN) << 6, n0 = (tid % tilesN) << 6;
  const int t = threadIdx.x, tc = t & 63, tr = t >> 6;
  __shared__ float L[64][65];
  const bool have = (k0 < d.K) && (n0 < d.N);
  if (have) {
    #pragma unroll
    for (int i = 0; i < 16; ++i) {
      int kk = tr + i * 4;
      L[kk][tc] = d.W[(size_t)(k0 + kk) * d.N + n0 + tc];
    }
  }
  __syncthreads();
  #pragma unroll
  for (int i = 0; i < 16; ++i) {
    int nn = tr + i * 4;
    u16 hi = 0, lo = 0;
    if (have) {
      float v = L[tc][nn];
      hi = bfr(v);
      lo = bfr(v - b2f(hi));
    }
    size_t idx = (size_t)(n0 + nn) * d.Kp + k0 + tc;
    d.Wt[idx] = hi;
    d.Wt[loOff + idx] = lo;
  }
}

// ---------------------------------------------------------------------------
// gemm_bt_mfma (split-bf16, 3-term): C = op(A)@Wt^T + bias, fp32-grade.
// A fp32 row-major, split hi/lo in-register during staging; Wt pre-split.
// Optional fused BN+ReLU on A (asc/ash, per-head if headed).
// Tile 128x128, BK=64, 4 waves (2x2), 16x16x32 MFMA, XOR-swizzled LDS.
// acc += Al*Bh + Ah*Bl + Ah*Bh   (Al*Bl ~2^-18 dropped)
// ---------------------------------------------------------------------------
__global__ __launch_bounds__(256) void gemm_bt_mfma_kernel(
    const float* __restrict__ A, const u16* __restrict__ Bw, size_t loOff,
    const float* __restrict__ bias, int biasN,
    const float* __restrict__ asc, const float* __restrict__ ash, int headed,
    float* __restrict__ C, int N, int K)
{
  __shared__ u16 Ah[128 * 64], Al[128 * 64];
  __shared__ u16 Bh[128 * 64], Bl[128 * 64];
  const int t  = threadIdx.x;
  const int n0 = blockIdx.x * 128;
  const int m0 = blockIdx.y * 128;

  int physOff[4];
  const float* gA[4]; const u16* gBh[4]; const u16* gBl[4];
  int colc[4];
  #pragma unroll
  for (int i = 0; i < 4; ++i) {
    int L = i * 256 + t;
    int row = L >> 3, c = L & 7;
    physOff[i] = (row * 8 + (c ^ (row & 7))) * 8;
    gA[i]  = A  + (size_t)(m0 + row) * K + c * 8;
    gBh[i] = Bw + (size_t)(n0 + row) * K + c * 8;
    gBl[i] = gBh[i] + loOff;
    colc[i] = (headed ? ((m0 + row) >> 10) * K : 0) + c * 8;
  }

  const int lane = t & 63, w = t >> 6;
  const int wm = (w >> 1) * 64, wn = (w & 1) * 64;
  const int q = lane >> 4, rl = lane & 15;

  f32x4 acc[4][4];
  const f32x4 z4 = {0.f, 0.f, 0.f, 0.f};
  #pragma unroll
  for (int i = 0; i < 4; ++i)
    #pragma unroll
    for (int j = 0; j < 4; ++j) acc[i][j] = z4;

  union U16x8 { u16 u[8]; float4 f4; };

  for (int k0 = 0; k0 < K; k0 += 64) {
    float ra[4][8]; uint4 rbh[4], rbl[4];
    #pragma unroll
    for (int i = 0; i < 4; ++i) {
      float4 a0 = ld4(gA[i]), a1 = ld4(gA[i] + 4); gA[i] += 64;
      ra[i][0]=a0.x; ra[i][1]=a0.y; ra[i][2]=a0.z; ra[i][3]=a0.w;
      ra[i][4]=a1.x; ra[i][5]=a1.y; ra[i][6]=a1.z; ra[i][7]=a1.w;
      rbh[i] = *(const uint4*)gBh[i]; gBh[i] += 64;
      rbl[i] = *(const uint4*)gBl[i]; gBl[i] += 64;
    }
    if (asc) {
      #pragma unroll
      for (int i = 0; i < 4; ++i) {
        int j0 = colc[i] + k0;
        #pragma unroll
        for (int j = 0; j < 8; ++j)
          ra[i][j] = fmaxf(0.f, fmaf(ra[i][j], asc[j0 + j], ash[j0 + j]));
      }
    }
    __syncthreads();
    #pragma unroll
    for (int i = 0; i < 4; ++i) {
      U16x8 ph, pl;
      #pragma unroll
      for (int j = 0; j < 8; ++j) {
        u16 h = bfr(ra[i][j]);
        ph.u[j] = h;
        pl.u[j] = bfr(ra[i][j] - b2f(h));
      }
      *(float4*)&Ah[physOff[i]] = ph.f4;
      *(float4*)&Al[physOff[i]] = pl.f4;
      *(uint4*)&Bh[physOff[i]] = rbh[i];
      *(uint4*)&Bl[physOff[i]] = rbl[i];
    }
    __syncthreads();
    #pragma unroll
    for (int kk = 0; kk < 2; ++kk) {
      short8 afh[4], afl[4], bfh[4], bfl[4];
      #pragma unroll
      for (int mt = 0; mt < 4; ++mt) {
        int r = wm + mt * 16 + rl;
        int cc = (kk * 4 + q) ^ (r & 7);
        afh[mt] = *(const short8*)&Ah[(r * 8 + cc) * 8];
        afl[mt] = *(const short8*)&Al[(r * 8 + cc) * 8];
      }
      #pragma unroll
      for (int nt = 0; nt < 4; ++nt) {
        int r = wn + nt * 16 + rl;
        int cc = (kk * 4 + q) ^ (r & 7);
        bfh[nt] = *(const short8*)&Bh[(r * 8 + cc) * 8];
        bfl[nt] = *(const short8*)&Bl[(r * 8 + cc) * 8];
      }
      #pragma unroll
      for (int mt = 0; mt < 4; ++mt)
        #pragma unroll
        for (int nt = 0; nt < 4; ++nt) {
          acc[mt][nt] = __builtin_amdgcn_mfma_f32_16x16x32_bf16(afl[mt], bfh[nt], acc[mt][nt], 0, 0, 0);
          acc[mt][nt] = __builtin_amdgcn_mfma_f32_16x16x32_bf16(afh[mt], bfl[nt], acc[mt][nt], 0, 0, 0);
          acc[mt][nt] = __builtin_amdgcn_mfma_f32_16x16x32_bf16(afh[mt], bfh[nt], acc[mt][nt], 0, 0, 0);
        }
    }
  }
  // epilogue: C/D layout col = lane&15, row = q*4 + reg  [m89-verified]
  #pragma unroll
  for (int nt = 0; nt < 4; ++nt) {
    int n = n0 + wn + nt * 16 + rl;
    float bv = (bias && n < biasN) ? bias[n] : 0.f;
    #pragma unroll
    for (int mt = 0; mt < 4; ++mt) {
      int m = m0 + wm + mt * 16 + q * 4;
      #pragma unroll
      for (int reg = 0; reg < 4; ++reg)
        C[(size_t)(m + reg) * N + n] = acc[mt][nt][reg] + bv;
    }
  }
}

// ---------------------------------------------------------------------------
// score_mfma: approx scores, single bf16 (selection only; rescue is exact).
// ---------------------------------------------------------------------------
__global__ __launch_bounds__(256) void score_mfma_kernel(
    const float* __restrict__ A, const float* __restrict__ Bq,
    float* __restrict__ C)
{
  __shared__ u16 At[128 * 64];
  __shared__ u16 Bt[128 * 64];
  const int t  = threadIdx.x;
  const int n0 = blockIdx.x * 128;
  const int m0 = blockIdx.y * 128;

  u16* ldsA[4]; u16* ldsB[4];
  const float* gA[4]; const float* gB[4];
  #pragma unroll
  for (int i = 0; i < 4; ++i) {
    int L = i * 256 + t;
    int row = L >> 3, c = L & 7;
    int phys = row * 8 + (c ^ (row & 7));
    ldsA[i] = &At[phys * 8]; ldsB[i] = &Bt[phys * 8];
    gA[i] = A  + (size_t)(m0 + row) * 512 + c * 8;
    gB[i] = Bq + (size_t)(n0 + row) * 512 + c * 8;
  }

  const int lane = t & 63, w = t >> 6;
  const int wm = (w >> 1) * 64, wn = (w & 1) * 64;
  const int q = lane >> 4, rl = lane & 15;

  f32x4 acc[4][4];
  const f32x4 z4 = {0.f, 0.f, 0.f, 0.f};
  #pragma unroll
  for (int i = 0; i < 4; ++i)
    #pragma unroll
    for (int j = 0; j < 4; ++j) acc[i][j] = z4;

  union U16x8 { u16 u[8]; float4 f4; };

  for (int k0 = 0; k0 < 512; k0 += 64) {
    float4 ra[4][2], rb[4][2];
    #pragma unroll
    for (int i = 0; i < 4; ++i) {
      ra[i][0] = ld4(gA[i]); ra[i][1] = ld4(gA[i] + 4);
      rb[i][0] = ld4(gB[i]); rb[i][1] = ld4(gB[i] + 4);
      gA[i] += 64; gB[i] += 64;
    }
    __syncthreads();
    #pragma unroll
    for (int i = 0; i < 4; ++i) {
      U16x8 pa, pb;
      pa.u[0]=bfr(ra[i][0].x); pa.u[1]=bfr(ra[i][0].y); pa.u[2]=bfr(ra[i][0].z); pa.u[3]=bfr(ra[i][0].w);
      pa.u[4]=bfr(ra[i][1].x); pa.u[5]=bfr(ra[i][1].y); pa.u[6]=bfr(ra[i][1].z); pa.u[7]=bfr(ra[i][1].w);
      pb.u[0]=bfr(rb[i][0].x); pb.u[1]=bfr(rb[i][0].y); pb.u[2]=bfr(rb[i][0].z); pb.u[3]=bfr(rb[i][0].w);
      pb.u[4]=bfr(rb[i][1].x); pb.u[5]=bfr(rb[i][1].y); pb.u[6]=bfr(rb[i][1].z); pb.u[7]=bfr(rb[i][1].w);
      *(float4*)ldsA[i] = pa.f4;
      *(float4*)ldsB[i] = pb.f4;
    }
    __syncthreads();
    #pragma unroll
    for (int kk = 0; kk < 2; ++kk) {
      short8 af[4], bfv[4];
      #pragma unroll
      for (int mt = 0; mt < 4; ++mt) {
        int r = wm + mt * 16 + rl;
        int cc = (kk * 4 + q) ^ (r & 7);
        af[mt] = *(const short8*)&At[(r * 8 + cc) * 8];
      }
      #pragma unroll
      for (int nt = 0; nt < 4; ++nt) {
        int r = wn + nt * 16 + rl;
        int cc = (kk * 4 + q) ^ (r & 7);
        bfv[nt] = *(const short8*)&Bt[(r * 8 + cc) * 8];
      }
      #pragma unroll
      for (int mt = 0; mt < 4; ++mt)
        #pragma unroll
        for (int nt = 0; nt < 4; ++nt)
          acc[mt][nt] = __builtin_amdgcn_mfma_f32_16x16x32_bf16(af[mt], bfv[nt], acc[mt][nt], 0, 0, 0);
    }
  }
  #pragma unroll
  for (int mt = 0; mt < 4; ++mt)
    #pragma unroll
    for (int nt = 0; nt < 4; ++nt) {
      int m = m0 + wm + mt * 16 + q * 4;
      int n = n0 + wn + nt * 16 + rl;
      #pragma unroll
      for (int reg = 0; reg < 4; ++reg)
        C[(size_t)(m + reg) * 32768 + n] = acc[mt][nt][reg];
    }
}

// ---------------------------------------------------------------------------
// BN column stats over 1024 rows -> scale/shift. 1024 thr, 16-way row split.
// cols >= gN forced to scale=shift=0 (keeps padded columns exactly zero).
// ---------------------------------------------------------------------------
__global__ __launch_bounds__(1024) void bn_stats_kernel(const float* __restrict__ X, int N,
    const float* __restrict__ gamma, const float* __restrict__ beta, int gstride, int gN,
    float* __restrict__ scale, float* __restrict__ shift)
{
  const int head = blockIdx.y;
  const float* Xh = X + (size_t)head * 1024 * N;
  const int lane = threadIdx.x & 63;
  const int col  = blockIdx.x * 64 + lane;
  const int rg   = threadIdx.x >> 6;      // 0..15
  float s = 0.f, ss = 0.f;
  const float* p = Xh + (size_t)(rg * 64) * N + col;
  for (int rr = 0; rr < 64; ++rr) { float v = *p; p += N; s += v; ss = fmaf(v, v, ss); }
  __shared__ float Ssum[16][64], Ssq[16][64];
  Ssum[rg][lane] = s; Ssq[rg][lane] = ss;
  __syncthreads();
  if (threadIdx.x < 64) {
    s = 0.f; ss = 0.f;
    #pragma unroll
    for (int r = 0; r < 16; ++r) { s += Ssum[r][lane]; ss += Ssq[r][lane]; }
    float mean = s * (1.f / 1024.f);
    float var  = ss * (1.f / 1024.f) - mean * mean;
    float sc = 0.f, sh = 0.f;
    if (col < gN) {
      sc = gamma[head * gstride + col] / sqrtf(var + 1e-5f);
      sh = beta[head * gstride + col] - mean * sc;
    }
    scale[head * N + col] = sc;
    shift[head * N + col] = sh;
  }
}

// out-of-place BN+ReLU for the fused head slice (N=512, 1024 rows)
__global__ void bn_apply512_kernel(float* __restrict__ dst, const float* __restrict__ src,
    const float* __restrict__ scale, const float* __restrict__ shift)
{
  int i = blockIdx.x * 256 + threadIdx.x;
  if (i >= 131072) return;
  size_t base = (size_t)i * 4;
  int col = (int)(base & 511);
  float4 v = ld4(src + base);
  v.x = fmaxf(0.f, fmaf(v.x, scale[col+0], shift[col+0]));
  v.y = fmaxf(0.f, fmaf(v.y, scale[col+1], shift[col+1]));
  v.z = fmaxf(0.f, fmaf(v.z, scale[col+2], shift[col+2]));
  v.w = fmaxf(0.f, fmaf(v.w, scale[col+3], shift[col+3]));
  *(float4*)&dst[base] = v;
}

__global__ void fuse_combine_kernel(const float* __restrict__ P,
    const float* __restrict__ fwr, const float* __restrict__ fb, float* __restrict__ H)
{
  int i = blockIdx.x * 256 + threadIdx.x;
  if (i >= 131072) return;
  size_t base = (size_t)i * 4;
  int c = (int)(base & 511);
  float4 p0 = ld4(P + base), p1 = ld4(P + 524288 + base), p2 = ld4(P + 1048576 + base);
  float4 w0 = ld4(fwr + c), w1 = ld4(fwr + 512 + c), w2 = ld4(fwr + 1024 + c), b = ld4(fb + c);
  float4 h0, h1, h2, h3;
  h0.x=p0.x+w0.x+b.x; h0.y=p0.y+w0.y+b.y; h0.z=p0.z+w0.z+b.z; h0.w=p0.w+w0.w+b.w;
  h1.x=p1.x+w1.x+b.x; h1.y=p1.y+w1.y+b.y; h1.z=p1.z+w1.z+b.z; h1.w=p1.w+w1.w+b.w;
  h2.x=p2.x+w2.x+b.x; h2.y=p2.y+w2.y+b.y; h2.z=p2.z+w2.z+b.z; h2.w=p2.w+w2.w+b.w;
  h3.x=p0.x+p1.x+p2.x+w0.x+w1.x+w2.x+b.x;
  h3.y=p0.y+p1.y+p2.y+w0.y+w1.y+w2.y+b.y;
  h3.z=p0.z+p1.z+p2.z+w0.z+w1.z+w2.z+b.z;
  h3.w=p0.w+p1.w+p2.w+w0.w+w1.w+w2.w+b.w;
  *(float4*)&H[base]           = h0;
  *(float4*)&H[524288 + base]  = h1;
  *(float4*)&H[1048576 + base] = h2;
  *(float4*)&H[1572864 + base] = h3;
}

__global__ void pack_gb_kernel(const float* __restrict__ sg, const float* __restrict__ sb,
    const float* __restrict__ g, const float* __restrict__ be,
    float* __restrict__ g4, float* __restrict__ b4)
{
  int i = blockIdx.x * 256 + threadIdx.x;
  if (i < 1536)      { g4[i] = sg[i];      b4[i] = sb[i]; }
  else if (i < 2048) { g4[i] = g[i-1536];  b4[i] = be[i-1536]; }
}

__global__ void row_sumsq_kernel(const float* __restrict__ X, float* __restrict__ out, int nrows)
{
  int row  = blockIdx.x * 4 + (threadIdx.x >> 6);
  int lane = threadIdx.x & 63;
  if (row >= nrows) return;
  const float* p = X + (size_t)row * 512 + lane * 8;
  float4 a = ld4(p), b = ld4(p + 4);
  float s = a.x*a.x + a.y*a.y + a.z*a.z + a.w*a.w
          + b.x*b.x + b.y*b.y + b.z*b.z + b.w*b.w;
  for (int off = 32; off; off >>= 1) s += __shfl_down(s, off, 64);
  if (lane == 0) out[row] = s;
}

// ---------------------------------------------------------------------------
// topk_scan1 / topk_rescue2 / knn_gather — unchanged (R3-verified).
// ---------------------------------------------------------------------------
__global__ __launch_bounds__(256) void topk_scan1_kernel(const float* __restrict__ S,
    const float* __restrict__ qn, const float* __restrict__ kn, int rowbase,
    float2* __restrict__ cand)
{
  const int row  = blockIdx.x;
  const int grow = rowbase + row;
  const int cb   = blockIdx.y;
  const float qnr = qn[grow];
  const float* Srow = S + (size_t)row * 32768 + cb * 8192;
  const float* knb  = kn + cb * 8192;
  const int t = threadIdx.x;
  const float INF = __builtin_inff();

  float vals[6]; int idxs[6];
  #pragma unroll
  for (int j = 0; j < 6; ++j) { vals[j] = INF; idxs[j] = 0x7fffffff; }

  auto ins = [&](float d2, int ci) {
    if (d2 < vals[5] || (d2 == vals[5] && ci < idxs[5])) {
      float cv = d2; int cc = ci;
      #pragma unroll
      for (int j = 0; j < 6; ++j) {
        bool less = (cv < vals[j]) || (cv == vals[j] && cc < idxs[j]);
        float tv = less ? vals[j] : cv; int ti = less ? idxs[j] : cc;
        vals[j] = less ? cv : vals[j]; idxs[j] = less ? cc : idxs[j];
        cv = tv; cc = ti;
      }
    }
  };

  #pragma unroll
  for (int i = 0; i < 8; ++i) {
    int c = (i * 256 + t) * 4;
    float4 s4 = ld4(Srow + c);
    float4 k4 = ld4(knb + c);
    int gcol = cb * 8192 + c;
    ins((qnr + k4.x) - 2.f * s4.x, gcol + 0);
    ins((qnr + k4.y) - 2.f * s4.y, gcol + 1);
    ins((qnr + k4.z) - 2.f * s4.z, gcol + 2);
    ins((qnr + k4.w) - 2.f * s4.w, gcol + 3);
  }

  __shared__ float Wv[4]; __shared__ int Wi[4];
  const int lane = t & 63, wid = t >> 6;
  for (int sel = 0; sel < 16; ++sel) {
    float bv = vals[0]; int bi = idxs[0];
    #pragma unroll
    for (int off = 32; off >= 1; off >>= 1) {
      float ov = __shfl_down(bv, off, 64);
      int   oi = __shfl_down(bi, off, 64);
      if (ov < bv || (ov == bv && oi < bi)) { bv = ov; bi = oi; }
    }
    if (lane == 0) { Wv[wid] = bv; Wi[wid] = bi; }
    __syncthreads();
    float gv = Wv[0]; int gi = Wi[0];
    #pragma unroll
    for (int w2 = 1; w2 < 4; ++w2) {
      float wv2 = Wv[w2]; int wi2 = Wi[w2];
      if (wv2 < gv || (wv2 == gv && wi2 < gi)) { gv = wv2; gi = wi2; }
    }
    if (t == 0) {
      float2 e; e.x = gv; e.y = __int_as_float(gi);
      cand[(size_t)grow * 64 + cb * 16 + sel] = e;
    }
    if (vals[0] == gv && idxs[0] == gi) {
      #pragma unroll
      for (int j = 0; j < 5; ++j) { vals[j] = vals[j+1]; idxs[j] = idxs[j+1]; }
      vals[5] = INF; idxs[5] = 0x7fffffff;
    }
    __syncthreads();
  }
}

__global__ __launch_bounds__(256) void topk_rescue2_kernel(const float2* __restrict__ cand,
    const float* __restrict__ fusedF, const float* __restrict__ queue,
    const float* __restrict__ qn, const float* __restrict__ kn,
    float* __restrict__ topd2, int* __restrict__ topidx)
{
  const int grow = blockIdx.x;
  const int t = threadIdx.x;
  const float INF = __builtin_inff();
  const float qnr = qn[grow];
  __shared__ int Ci[16]; __shared__ float Cd[16];

  if (t < 64) {
    float2 e = cand[(size_t)grow * 64 + t];
    float v = e.x; int id = __float_as_int(e.y);
    for (int sel = 0; sel < 16; ++sel) {
      float bv = v; int bi = id;
      #pragma unroll
      for (int off = 32; off >= 1; off >>= 1) {
        float ov = __shfl_down(bv, off, 64);
        int   oi = __shfl_down(bi, off, 64);
        if (ov < bv || (ov == bv && oi < bi)) { bv = ov; bi = oi; }
      }
      bv = __shfl(bv, 0, 64); bi = __shfl(bi, 0, 64);
      if (t == 0) Ci[sel] = bi;
      if (id == bi) { v = INF; id = 0x7fffffff; }
    }
  }
  __syncthreads();

  {
    int c = t >> 4, s = t & 15;
    int qi = Ci[c];
    const float* qp = queue  + (size_t)qi * 512 + s * 32;
    const float* fp = fusedF + (size_t)grow * 512 + s * 32;
    float dot = 0.f;
    #pragma unroll
    for (int j = 0; j < 8; ++j) {
      float4 a = ld4(fp + j*4); float4 b = ld4(qp + j*4);
      dot += a.x*b.x + a.y*b.y + a.z*b.z + a.w*b.w;
    }
    #pragma unroll
    for (int off = 8; off >= 1; off >>= 1) dot += __shfl_down(dot, off, 16);
    if (s == 0) Cd[c] = qnr + kn[qi] - 2.f * dot;
  }
  __syncthreads();

  if (t < 64) {
    float v = (t < 16) ? Cd[t] : INF;
    int  id = (t < 16) ? Ci[t] : 0x7fffffff;
    for (int sel = 0; sel < TK; ++sel) {
      float bv = v; int bi = id;
      #pragma unroll
      for (int off = 32; off >= 1; off >>= 1) {
        float ov = __shfl_down(bv, off, 64);
        int   oi = __shfl_down(bi, off, 64);
        if (ov < bv || (ov == bv && oi < bi)) { bv = ov; bi = oi; }
      }
      bv = __shfl(bv, 0, 64); bi = __shfl(bi, 0, 64);
      if (t == 0) { topd2[grow*TK + sel] = bv; topidx[grow*TK + sel] = bi; }
      if (id == bi) { v = INF; id = 0x7fffffff; }
    }
  }
}

__global__ void knn_gather_kernel(const float* __restrict__ topd2, const int* __restrict__ topidx,
    const float* __restrict__ queue, float* __restrict__ neigh)
{
  const int row = blockIdx.x;
  const int t = threadIdx.x;   // 64
  __shared__ float ls[TK]; __shared__ float wv[TK]; __shared__ int wid[TK];
  if (t < TK) {
    float d = sqrtf(fmaxf(topd2[row*TK + t], 0.f));
    ls[t]  = -d / 0.07f;
    wid[t] = topidx[row*TK + t];
  }
  __syncthreads();
  if (t < TK) {
    float m = ls[0];
    #pragma unroll
    for (int j = 1; j < TK; ++j) m = fmaxf(m, ls[j]);
    wv[t] = __expf(ls[t] - m);
  }
  __syncthreads();
  float ssum = 0.f;
  #pragma unroll
  for (int j = 0; j < TK; ++j) ssum += wv[j];
  float inv = 1.f / ssum;
  #pragma unroll
  for (int u = 0; u < 8; ++u) {
    int c = u * 64 + t;
    float acc = 0.f;
    #pragma unroll
    for (int k = 0; k < TK; ++k)
      acc = fmaf(wv[k] * inv, queue[(size_t)wid[k] * 512 + c], acc);
    neigh[(size_t)row * 512 + c] = acc;
  }
}

// out[r,c] = b2[c] + sum_k relu(Z[r,k]*sc+sh) * W2[k,c]; head = r>>10.
__global__ void gemm_n18_kernel(const float* __restrict__ Z,
    const float* __restrict__ sc, const float* __restrict__ sh,
    const float* __restrict__ W2, const float* __restrict__ b2,
    float* __restrict__ out, int Mrows)
{
  int o = blockIdx.x * 256 + threadIdx.x;
  if (o >= Mrows * 18) return;
  int r = o / 18, c = o - r * 18;
  const float* zp = Z + (size_t)r * 512;
  const float* scp = sc + (r >> 10) * 512;
  const float* shp = sh + (r >> 10) * 512;
  float acc = b2[c];
  #pragma unroll 8
  for (int k = 0; k < 512; ++k) {
    float z = fmaxf(0.f, fmaf(zp[k], scp[k], shp[k]));
    acc = fmaf(z, W2[k*18 + c], acc);
  }
  out[o] = acc;
}

// ---------------------------------------------------------------------------
extern "C" void kernel_launch(void* const* d_in, const int* in_sizes, int n_in,
                              void* d_out, int out_size, void* d_ws, size_t ws_size,
                              hipStream_t stream)
{
  #define IN(i) ((const float*)d_in[i])
  const float* img_feat = IN(0);
  const float* option   = IN(1);
  const float* semantic = IN(2);
  const float* queue    = IN(3);
  const float* vae_w1 = IN(4);  const float* vae_b1 = IN(5);
  const float* vae_g1 = IN(6);  const float* vae_be1 = IN(7);
  const float* vae_w2 = IN(8);  const float* vae_b2 = IN(9);
  const float* opt_w1 = IN(10); const float* opt_b1 = IN(11);
  const float* opt_g1 = IN(12); const float* opt_be1 = IN(13);
  const float* opt_w2 = IN(14); const float* opt_b2 = IN(15);
  const float* opt_g2 = IN(16); const float* opt_be2 = IN(17);
  const float* sem_w1 = IN(18); const float* sem_b1 = IN(19);
  const float* sem_g1 = IN(20); const float* sem_be1 = IN(21);
  const float* sem_w2 = IN(22); const float* sem_b2 = IN(23);
  const float* sem_g2 = IN(24); const float* sem_be2 = IN(25);
  const float* fus_w = IN(26);  const float* fus_b = IN(27);
  const float* fus_g = IN(28);  const float* fus_be = IN(29);
  const float* fus_sg = IN(30); const float* fus_sb = IN(31);
  const float* cls_w1 = IN(32); const float* cls_b1 = IN(33);
  const float* cls_g = IN(34);  const float* cls_be = IN(35);
  const float* cls_w2 = IN(36); const float* cls_b2 = IN(37);

  float* ws = (float*)d_ws;
  size_t off = 0;
  auto alloc = [&](size_t n) { float* p = ws + off; off += (n + 255) & ~(size_t)255; return p; };

  const int srows = 128;   // 16 MB stripe; total ws ~61 MB with split weights

  float* S    = alloc((size_t)srows * 32768);
  float* H    = alloc(4 * 1024 * 512);
  float* Z4   = alloc(4 * 1024 * 512);
  float* t1   = alloc(1024 * 512);      // also fusedb (after VAE2 is done)
  float* img  = alloc(1024 * 512);      // also Z1 (after FUS0 is done)
  float* o1p  = alloc(1024 * 256);
  float* optb = alloc(1024 * 512);      // also neigh (after FUS1 is done)
  float* s1p  = alloc(1024 * 256);
  float* semb = alloc(1024 * 512);
  float* P    = alloc(3 * 1024 * 512);
  // split bf16 transposed weights: alloc(elems) floats == 2*elems u16 (hi||lo)
  u16* vae_w1t = (u16*)alloc(1048576);
  u16* vae_w2t = (u16*)alloc(262144);
  u16* opt_w1t = (u16*)alloc(196608);
  u16* opt_w2t = (u16*)alloc(131072);
  u16* sem_w1t = (u16*)alloc(196608);
  u16* sem_w2t = (u16*)alloc(131072);
  u16* fus0t   = (u16*)alloc(262144);
  u16* fus1t   = (u16*)alloc(262144);
  u16* fus2t   = (u16*)alloc(262144);
  u16* cls_w1t = (u16*)alloc(262144);
  float* qn   = alloc(1024);
  float* kn   = alloc(32768);
  float2* cand = (float2*)alloc(1024 * 64 * 2);
  float* scv  = alloc(512);  float* shv  = alloc(512);
  float* sco1 = alloc(256);  float* sho1 = alloc(256);
  float* sco2 = alloc(512);  float* sho2 = alloc(512);
  float* scs1 = alloc(256);  float* shs1 = alloc(256);
  float* scs2 = alloc(512);  float* shs2 = alloc(512);
  float* scf  = alloc(4*512); float* shf = alloc(4*512);
  float* scc4 = alloc(4*512); float* shc4 = alloc(4*512);
  float* scc1 = alloc(512);  float* shc1 = alloc(512);
  float* g4   = alloc(4*512); float* b4  = alloc(4*512);
  float* topd2 = alloc(1024 * TK);
  int*   topidx = (int*)alloc(1024 * TK);

  float* fusedb = t1;
  float* Z1     = img;
  float* neigh  = optb;

  dim3 blk(256);

  // --- weight transpose+pack (one launch, split hi/lo) ---
  TDs ds;
  ds.d[0] = { vae_w1, vae_w1t, 2048, 2048, 512, 512 };
  ds.d[1] = { vae_w2, vae_w2t,  512,  512, 512, 512 };
  ds.d[2] = { opt_w1, opt_w1t,  768,  768, 192, 256 };
  ds.d[3] = { opt_w2, opt_w2t,  192,  256, 512, 512 };
  ds.d[4] = { sem_w1, sem_w1t,  768,  768, 192, 256 };
  ds.d[5] = { sem_w2, sem_w2t,  192,  256, 512, 512 };
  ds.d[6] = { fus_w,            fus0t, 512, 512, 512, 512 };
  ds.d[7] = { fus_w + 262144,   fus1t, 512, 512, 512, 512 };
  ds.d[8] = { fus_w + 524288,   fus2t, 512, 512, 512, 512 };
  ds.d[9] = { cls_w1, cls_w1t,  512,  512, 512, 512 };
  wt_transpose_kernel<<<dim3(256, 10), blk, 0, stream>>>(ds);

  // --- VAE: t1 = img_feat@W1+b1; img = relu(bn(t1))@W2+b2 (BN fused in staging)
  gemm_bt_mfma_kernel<<<dim3(4,8), blk, 0, stream>>>(img_feat, vae_w1t, 1048576, vae_b1, 512, nullptr, nullptr, 0, t1, 512, 2048);
  bn_stats_kernel<<<dim3(8,1), dim3(1024), 0, stream>>>(t1, 512, vae_g1, vae_be1, 0, 512, scv, shv);
  gemm_bt_mfma_kernel<<<dim3(4,8), blk, 0, stream>>>(t1, vae_w2t, 262144, vae_b2, 512, scv, shv, 0, img, 512, 512);
  // --- option encoder
  gemm_bt_mfma_kernel<<<dim3(2,8), blk, 0, stream>>>(option, opt_w1t, 196608, opt_b1, 192, nullptr, nullptr, 0, o1p, 256, 768);
  bn_stats_kernel<<<dim3(4,1), dim3(1024), 0, stream>>>(o1p, 256, opt_g1, opt_be1, 0, 192, sco1, sho1);
  gemm_bt_mfma_kernel<<<dim3(4,8), blk, 0, stream>>>(o1p, opt_w2t, 131072, opt_b2, 512, sco1, sho1, 0, optb, 512, 256);
  bn_stats_kernel<<<dim3(8,1), dim3(1024), 0, stream>>>(optb, 512, opt_g2, opt_be2, 0, 512, sco2, sho2);
  // --- semantic encoder
  gemm_bt_mfma_kernel<<<dim3(2,8), blk, 0, stream>>>(semantic, sem_w1t, 196608, sem_b1, 192, nullptr, nullptr, 0, s1p, 256, 768);
  bn_stats_kernel<<<dim3(4,1), dim3(1024), 0, stream>>>(s1p, 256, sem_g1, sem_be1, 0, 192, scs1, shs1);
  gemm_bt_mfma_kernel<<<dim3(4,8), blk, 0, stream>>>(s1p, sem_w2t, 131072, sem_b2, 512, scs1, shs1, 0, semb, 512, 256);
  bn_stats_kernel<<<dim3(8,1), dim3(1024), 0, stream>>>(semb, 512, sem_g2, sem_be2, 0, 512, scs2, shs2);
  // --- fusion partials (BN of optb/semb fused into staging)
  gemm_bt_mfma_kernel<<<dim3(4,8), blk, 0, stream>>>(img,  fus0t, 262144, nullptr, 0, nullptr, nullptr, 0, P,           512, 512);
  gemm_bt_mfma_kernel<<<dim3(4,8), blk, 0, stream>>>(optb, fus1t, 262144, nullptr, 0, sco2, sho2, 0, P + 524288,  512, 512);
  gemm_bt_mfma_kernel<<<dim3(4,8), blk, 0, stream>>>(semb, fus2t, 262144, nullptr, 0, scs2, shs2, 0, P + 1048576, 512, 512);
  fuse_combine_kernel<<<dim3(512), blk, 0, stream>>>(P, fus_w + 1536*512, fus_b, H);
  pack_gb_kernel<<<dim3(8), blk, 0, stream>>>(fus_sg, fus_sb, fus_g, fus_be, g4, b4);
  bn_stats_kernel<<<dim3(8,4), dim3(1024), 0, stream>>>(H, 512, g4, b4, 512, 512, scf, shf);
  bn_apply512_kernel<<<dim3(512), blk, 0, stream>>>(fusedb, H + (size_t)3*1024*512, scf + 1536, shf + 1536);
  // --- classifier heads 0..3 (fusion BN fused into staging, per-head scale)
  gemm_bt_mfma_kernel<<<dim3(4,32), blk, 0, stream>>>(H, cls_w1t, 262144, cls_b1, 512, scf, shf, 1, Z4, 512, 512);
  bn_stats_kernel<<<dim3(8,4), dim3(1024), 0, stream>>>(Z4, 512, cls_g, cls_be, 0, 512, scc4, shc4);
  gemm_n18_kernel<<<dim3(288), blk, 0, stream>>>(Z4, scc4, shc4, cls_w2, cls_b2, (float*)d_out, 4096);
  // --- kNN retrieval
  row_sumsq_kernel<<<dim3(256), blk, 0, stream>>>(fusedb, qn, 1024);
  row_sumsq_kernel<<<dim3(8192), blk, 0, stream>>>(queue, kn, 32768);
  for (int sbase = 0; sbase < 1024; sbase += srows) {
    score_mfma_kernel<<<dim3(256, srows/128), blk, 0, stream>>>(fusedb + (size_t)sbase*512, queue, S);
    topk_scan1_kernel<<<dim3(srows, 4), blk, 0, stream>>>(S, qn, kn, sbase, cand);
  }
  topk_rescue2_kernel<<<dim3(1024), blk, 0, stream>>>(cand, fusedb, queue, qn, kn, topd2, topidx);
  knn_gather_kernel<<<dim3(1024), dim3(64), 0, stream>>>(topd2, topidx, queue, neigh);
  // --- classifier head 4
  gemm_bt_mfma_kernel<<<dim3(4,8), blk, 0, stream>>>(neigh, cls_w1t, 262144, cls_b1, 512, nullptr, nullptr, 0, Z1, 512, 512);
  bn_stats_kernel<<<dim3(8,1), dim3(1024), 0, stream>>>(Z1, 512, cls_g, cls_be, 0, 512, scc1, shc1);
  gemm_n18_kernel<<<dim3(72), blk, 0, stream>>>(Z1, scc1, shc1, cls_w2, cls_b2, (float*)d_out + 4*1024*18, 1024);
  #undef IN
}

// Round 7
// 1074.220 us; speedup vs baseline: 1.1552x; 1.1552x over previous
//
#include <hip/hip_runtime.h>
#include <cstdint>
#include <cstddef>

#define TK 10

typedef unsigned short u16;
typedef __attribute__((ext_vector_type(8))) short short8;
typedef __attribute__((ext_vector_type(4))) float f32x4;

__device__ __forceinline__ float4 ld4(const float* p){ return *(const float4*)p; }

// fp32 -> bf16 round-to-nearest-even, and back
__device__ __forceinline__ u16 bfr(float x){
  unsigned u = __float_as_uint(x);
  return (u16)((u + 0x7FFFu + ((u >> 16) & 1u)) >> 16);
}
__device__ __forceinline__ float b2f(u16 h){
  unsigned u = ((unsigned)h) << 16;
  return __uint_as_float(u);
}

// ---------------------------------------------------------------------------
// wt_transpose: one launch packs all weights W[K,N] fp32 -> Wt (transposed,
// zero-padded) as SPLIT bf16: hi at [0, Np*Kp), lo at [Np*Kp, 2*Np*Kp).
// ---------------------------------------------------------------------------
struct TD { const float* W; u16* Wt; int K, Kp, N, Np; };
struct TDs { TD d[10]; };

__global__ __launch_bounds__(256) void wt_transpose_kernel(TDs ds)
{
  TD d = ds.d[blockIdx.y];
  const size_t loOff = (size_t)d.Np * d.Kp;
  const int tilesN = d.Np >> 6;
  const int tiles  = (d.Kp >> 6) * tilesN;
  const int tid = blockIdx.x;
  if (tid >= tiles) return;
  const int k0 = (tid / tilesN) << 6, n0 = (tid % tilesN) << 6;
  const int t = threadIdx.x, tc = t & 63, tr = t >> 6;
  __shared__ float L[64][65];
  const bool have = (k0 < d.K) && (n0 < d.N);
  if (have) {
    #pragma unroll
    for (int i = 0; i < 16; ++i) {
      int kk = tr + i * 4;
      L[kk][tc] = d.W[(size_t)(k0 + kk) * d.N + n0 + tc];
    }
  }
  __syncthreads();
  #pragma unroll
  for (int i = 0; i < 16; ++i) {
    int nn = tr + i * 4;
    u16 hi = 0, lo = 0;
    if (have) {
      float v = L[tc][nn];
      hi = bfr(v);
      lo = bfr(v - b2f(hi));
    }
    size_t idx = (size_t)(n0 + nn) * d.Kp + k0 + tc;
    d.Wt[idx] = hi;
    d.Wt[loOff + idx] = lo;
  }
}

// ---------------------------------------------------------------------------
// gemm_bt_mfma v2 (split-bf16 3-term, double-buffered, split-K):
// C = op(A)@Wt^T + bias. Tile 128x128, BK=32, LDS 2x(Ah,Al,Bh,Bl)=64KB.
// Per iter: prefetch next k-tile to regs -> compute current -> stage -> 1 barrier.
// gridDim.z>1: atomicAdd into pre-zeroed C, bias added by z==0 only.
// acc += Al*Bh + Ah*Bl + Ah*Bh   (Al*Bl ~2^-18 dropped)
// ---------------------------------------------------------------------------
__global__ __launch_bounds__(256) void gemm_bt_mfma_kernel(
    const float* __restrict__ A, const u16* __restrict__ Bw, size_t loOff,
    const float* __restrict__ bias, int biasN,
    const float* __restrict__ asc, const float* __restrict__ ash, int headed,
    float* __restrict__ C, int N, int K)
{
  __shared__ u16 AhL[2][128*32], AlL[2][128*32], BhL[2][128*32], BlL[2][128*32];
  const int t  = threadIdx.x;
  const int n0 = blockIdx.x * 128;
  const int m0 = blockIdx.y * 128;
  const int kchunk = K / gridDim.z;
  const int kbeg = blockIdx.z * kchunk;
  const int iters = kchunk >> 5;

  int physOff[2]; const float* gA[2]; const u16* gBh[2]; const u16* gBl[2];
  int colc[2];
  #pragma unroll
  for (int i = 0; i < 2; ++i) {
    int L = i * 256 + t;
    int row = L >> 2, c = L & 3;
    physOff[i] = (row * 4 + (c ^ (row & 3))) * 8;
    gA[i]  = A  + (size_t)(m0 + row) * K + kbeg + c * 8;
    gBh[i] = Bw + (size_t)(n0 + row) * K + kbeg + c * 8;
    gBl[i] = gBh[i] + loOff;
    colc[i] = (headed ? ((m0 + row) >> 10) * K : 0) + kbeg + c * 8;
  }

  const int lane = t & 63, w = t >> 6;
  const int wm = (w >> 1) * 64, wn = (w & 1) * 64;
  const int q = lane >> 4, rl = lane & 15;

  f32x4 acc[4][4];
  const f32x4 z4 = {0.f, 0.f, 0.f, 0.f};
  #pragma unroll
  for (int i = 0; i < 4; ++i)
    #pragma unroll
    for (int j = 0; j < 4; ++j) acc[i][j] = z4;

  union U16x8 { u16 u[8]; float4 f4; };
  float ra[2][8]; uint4 rbh[2], rbl[2];

  auto prefetch = [&](int it) {
    #pragma unroll
    for (int i = 0; i < 2; ++i) {
      const float* pa = gA[i] + it * 32;
      float4 a0 = ld4(pa), a1 = ld4(pa + 4);
      ra[i][0]=a0.x; ra[i][1]=a0.y; ra[i][2]=a0.z; ra[i][3]=a0.w;
      ra[i][4]=a1.x; ra[i][5]=a1.y; ra[i][6]=a1.z; ra[i][7]=a1.w;
      rbh[i] = *(const uint4*)(gBh[i] + it * 32);
      rbl[i] = *(const uint4*)(gBl[i] + it * 32);
    }
    if (asc) {
      #pragma unroll
      for (int i = 0; i < 2; ++i) {
        int j0 = colc[i] + it * 32;
        #pragma unroll
        for (int j = 0; j < 8; ++j)
          ra[i][j] = fmaxf(0.f, fmaf(ra[i][j], asc[j0 + j], ash[j0 + j]));
      }
    }
  };
  auto stage = [&](int buf) {
    #pragma unroll
    for (int i = 0; i < 2; ++i) {
      U16x8 ph, pl;
      #pragma unroll
      for (int j = 0; j < 8; ++j) {
        u16 h = bfr(ra[i][j]);
        ph.u[j] = h;
        pl.u[j] = bfr(ra[i][j] - b2f(h));
      }
      *(float4*)&AhL[buf][physOff[i]] = ph.f4;
      *(float4*)&AlL[buf][physOff[i]] = pl.f4;
      *(uint4*)&BhL[buf][physOff[i]] = rbh[i];
      *(uint4*)&BlL[buf][physOff[i]] = rbl[i];
    }
  };
  auto compute = [&](int buf) {
    short8 afh[4], afl[4], bfh[4], bfl[4];
    #pragma unroll
    for (int mt = 0; mt < 4; ++mt) {
      int r = wm + mt * 16 + rl;
      int cc = q ^ (r & 3);
      afh[mt] = *(const short8*)&AhL[buf][(r * 4 + cc) * 8];
      afl[mt] = *(const short8*)&AlL[buf][(r * 4 + cc) * 8];
    }
    #pragma unroll
    for (int nt = 0; nt < 4; ++nt) {
      int r = wn + nt * 16 + rl;
      int cc = q ^ (r & 3);
      bfh[nt] = *(const short8*)&BhL[buf][(r * 4 + cc) * 8];
      bfl[nt] = *(const short8*)&BlL[buf][(r * 4 + cc) * 8];
    }
    #pragma unroll
    for (int mt = 0; mt < 4; ++mt)
      #pragma unroll
      for (int nt = 0; nt < 4; ++nt) {
        acc[mt][nt] = __builtin_amdgcn_mfma_f32_16x16x32_bf16(afl[mt], bfh[nt], acc[mt][nt], 0, 0, 0);
        acc[mt][nt] = __builtin_amdgcn_mfma_f32_16x16x32_bf16(afh[mt], bfl[nt], acc[mt][nt], 0, 0, 0);
        acc[mt][nt] = __builtin_amdgcn_mfma_f32_16x16x32_bf16(afh[mt], bfh[nt], acc[mt][nt], 0, 0, 0);
      }
  };

  prefetch(0);
  stage(0);
  __syncthreads();
  int buf = 0;
  for (int it = 0; it < iters; ++it) {
    if (it + 1 < iters) prefetch(it + 1);
    compute(buf);
    if (it + 1 < iters) { stage(buf ^ 1); __syncthreads(); buf ^= 1; }
  }

  // epilogue: C/D layout col = lane&15, row = q*4 + reg  [m89-verified]
  if (gridDim.z == 1) {
    #pragma unroll
    for (int nt = 0; nt < 4; ++nt) {
      int n = n0 + wn + nt * 16 + rl;
      float bv = (bias && n < biasN) ? bias[n] : 0.f;
      #pragma unroll
      for (int mt = 0; mt < 4; ++mt) {
        int m = m0 + wm + mt * 16 + q * 4;
        #pragma unroll
        for (int reg = 0; reg < 4; ++reg)
          C[(size_t)(m + reg) * N + n] = acc[mt][nt][reg] + bv;
      }
    }
  } else {
    #pragma unroll
    for (int nt = 0; nt < 4; ++nt) {
      int n = n0 + wn + nt * 16 + rl;
      float bv = (bias && blockIdx.z == 0 && n < biasN) ? bias[n] : 0.f;
      #pragma unroll
      for (int mt = 0; mt < 4; ++mt) {
        int m = m0 + wm + mt * 16 + q * 4;
        #pragma unroll
        for (int reg = 0; reg < 4; ++reg)
          atomicAdd(&C[(size_t)(m + reg) * N + n], acc[mt][nt][reg] + bv);
      }
    }
  }
}

// ---------------------------------------------------------------------------
// score_mfma: approx scores, single bf16 (selection only; rescue is exact).
// ---------------------------------------------------------------------------
__global__ __launch_bounds__(256) void score_mfma_kernel(
    const float* __restrict__ A, const float* __restrict__ Bq,
    float* __restrict__ C)
{
  __shared__ u16 At[128 * 64];
  __shared__ u16 Bt[128 * 64];
  const int t  = threadIdx.x;
  const int n0 = blockIdx.x * 128;
  const int m0 = blockIdx.y * 128;

  u16* ldsA[4]; u16* ldsB[4];
  const float* gA[4]; const float* gB[4];
  #pragma unroll
  for (int i = 0; i < 4; ++i) {
    int L = i * 256 + t;
    int row = L >> 3, c = L & 7;
    int phys = row * 8 + (c ^ (row & 7));
    ldsA[i] = &At[phys * 8]; ldsB[i] = &Bt[phys * 8];
    gA[i] = A  + (size_t)(m0 + row) * 512 + c * 8;
    gB[i] = Bq + (size_t)(n0 + row) * 512 + c * 8;
  }

  const int lane = t & 63, w = t >> 6;
  const int wm = (w >> 1) * 64, wn = (w & 1) * 64;
  const int q = lane >> 4, rl = lane & 15;

  f32x4 acc[4][4];
  const f32x4 z4 = {0.f, 0.f, 0.f, 0.f};
  #pragma unroll
  for (int i = 0; i < 4; ++i)
    #pragma unroll
    for (int j = 0; j < 4; ++j) acc[i][j] = z4;

  union U16x8 { u16 u[8]; float4 f4; };

  for (int k0 = 0; k0 < 512; k0 += 64) {
    float4 ra[4][2], rb[4][2];
    #pragma unroll
    for (int i = 0; i < 4; ++i) {
      ra[i][0] = ld4(gA[i]); ra[i][1] = ld4(gA[i] + 4);
      rb[i][0] = ld4(gB[i]); rb[i][1] = ld4(gB[i] + 4);
      gA[i] += 64; gB[i] += 64;
    }
    __syncthreads();
    #pragma unroll
    for (int i = 0; i < 4; ++i) {
      U16x8 pa, pb;
      pa.u[0]=bfr(ra[i][0].x); pa.u[1]=bfr(ra[i][0].y); pa.u[2]=bfr(ra[i][0].z); pa.u[3]=bfr(ra[i][0].w);
      pa.u[4]=bfr(ra[i][1].x); pa.u[5]=bfr(ra[i][1].y); pa.u[6]=bfr(ra[i][1].z); pa.u[7]=bfr(ra[i][1].w);
      pb.u[0]=bfr(rb[i][0].x); pb.u[1]=bfr(rb[i][0].y); pb.u[2]=bfr(rb[i][0].z); pb.u[3]=bfr(rb[i][0].w);
      pb.u[4]=bfr(rb[i][1].x); pb.u[5]=bfr(rb[i][1].y); pb.u[6]=bfr(rb[i][1].z); pb.u[7]=bfr(rb[i][1].w);
      *(float4*)ldsA[i] = pa.f4;
      *(float4*)ldsB[i] = pb.f4;
    }
    __syncthreads();
    #pragma unroll
    for (int kk = 0; kk < 2; ++kk) {
      short8 af[4], bfv[4];
      #pragma unroll
      for (int mt = 0; mt < 4; ++mt) {
        int r = wm + mt * 16 + rl;
        int cc = (kk * 4 + q) ^ (r & 7);
        af[mt] = *(const short8*)&At[(r * 8 + cc) * 8];
      }
      #pragma unroll
      for (int nt = 0; nt < 4; ++nt) {
        int r = wn + nt * 16 + rl;
        int cc = (kk * 4 + q) ^ (r & 7);
        bfv[nt] = *(const short8*)&Bt[(r * 8 + cc) * 8];
      }
      #pragma unroll
      for (int mt = 0; mt < 4; ++mt)
        #pragma unroll
        for (int nt = 0; nt < 4; ++nt)
          acc[mt][nt] = __builtin_amdgcn_mfma_f32_16x16x32_bf16(af[mt], bfv[nt], acc[mt][nt], 0, 0, 0);
    }
  }
  #pragma unroll
  for (int mt = 0; mt < 4; ++mt)
    #pragma unroll
    for (int nt = 0; nt < 4; ++nt) {
      int m = m0 + wm + mt * 16 + q * 4;
      int n = n0 + wn + nt * 16 + rl;
      #pragma unroll
      for (int reg = 0; reg < 4; ++reg)
        C[(size_t)(m + reg) * 32768 + n] = acc[mt][nt][reg];
    }
}

// ---------------------------------------------------------------------------
// BN column stats over 1024 rows -> scale/shift. 1024 thr, 16-way row split.
// ---------------------------------------------------------------------------
__global__ __launch_bounds__(1024) void bn_stats_kernel(const float* __restrict__ X, int N,
    const float* __restrict__ gamma, const float* __restrict__ beta, int gstride, int gN,
    float* __restrict__ scale, float* __restrict__ shift)
{
  const int head = blockIdx.y;
  const float* Xh = X + (size_t)head * 1024 * N;
  const int lane = threadIdx.x & 63;
  const int col  = blockIdx.x * 64 + lane;
  const int rg   = threadIdx.x >> 6;      // 0..15
  float s = 0.f, ss = 0.f;
  const float* p = Xh + (size_t)(rg * 64) * N + col;
  for (int rr = 0; rr < 64; ++rr) { float v = *p; p += N; s += v; ss = fmaf(v, v, ss); }
  __shared__ float Ssum[16][64], Ssq[16][64];
  Ssum[rg][lane] = s; Ssq[rg][lane] = ss;
  __syncthreads();
  if (threadIdx.x < 64) {
    s = 0.f; ss = 0.f;
    #pragma unroll
    for (int r = 0; r < 16; ++r) { s += Ssum[r][lane]; ss += Ssq[r][lane]; }
    float mean = s * (1.f / 1024.f);
    float var  = ss * (1.f / 1024.f) - mean * mean;
    float sc = 0.f, sh = 0.f;
    if (col < gN) {
      sc = gamma[head * gstride + col] / sqrtf(var + 1e-5f);
      sh = beta[head * gstride + col] - mean * sc;
    }
    scale[head * N + col] = sc;
    shift[head * N + col] = sh;
  }
}

// out-of-place BN+ReLU for the fused head slice (N=512, 1024 rows)
__global__ void bn_apply512_kernel(float* __restrict__ dst, const float* __restrict__ src,
    const float* __restrict__ scale, const float* __restrict__ shift)
{
  int i = blockIdx.x * 256 + threadIdx.x;
  if (i >= 131072) return;
  size_t base = (size_t)i * 4;
  int col = (int)(base & 511);
  float4 v = ld4(src + base);
  v.x = fmaxf(0.f, fmaf(v.x, scale[col+0], shift[col+0]));
  v.y = fmaxf(0.f, fmaf(v.y, scale[col+1], shift[col+1]));
  v.z = fmaxf(0.f, fmaf(v.z, scale[col+2], shift[col+2]));
  v.w = fmaxf(0.f, fmaf(v.w, scale[col+3], shift[col+3]));
  *(float4*)&dst[base] = v;
}

__global__ void fuse_combine_kernel(const float* __restrict__ P,
    const float* __restrict__ fwr, const float* __restrict__ fb, float* __restrict__ H)
{
  int i = blockIdx.x * 256 + threadIdx.x;
  if (i >= 131072) return;
  size_t base = (size_t)i * 4;
  int c = (int)(base & 511);
  float4 p0 = ld4(P + base), p1 = ld4(P + 524288 + base), p2 = ld4(P + 1048576 + base);
  float4 w0 = ld4(fwr + c), w1 = ld4(fwr + 512 + c), w2 = ld4(fwr + 1024 + c), b = ld4(fb + c);
  float4 h0, h1, h2, h3;
  h0.x=p0.x+w0.x+b.x; h0.y=p0.y+w0.y+b.y; h0.z=p0.z+w0.z+b.z; h0.w=p0.w+w0.w+b.w;
  h1.x=p1.x+w1.x+b.x; h1.y=p1.y+w1.y+b.y; h1.z=p1.z+w1.z+b.z; h1.w=p1.w+w1.w+b.w;
  h2.x=p2.x+w2.x+b.x; h2.y=p2.y+w2.y+b.y; h2.z=p2.z+w2.z+b.z; h2.w=p2.w+w2.w+b.w;
  h3.x=p0.x+p1.x+p2.x+w0.x+w1.x+w2.x+b.x;
  h3.y=p0.y+p1.y+p2.y+w0.y+w1.y+w2.y+b.y;
  h3.z=p0.z+p1.z+p2.z+w0.z+w1.z+w2.z+b.z;
  h3.w=p0.w+p1.w+p2.w+w0.w+w1.w+w2.w+b.w;
  *(float4*)&H[base]           = h0;
  *(float4*)&H[524288 + base]  = h1;
  *(float4*)&H[1048576 + base] = h2;
  *(float4*)&H[1572864 + base] = h3;
}

__global__ void pack_gb_kernel(const float* __restrict__ sg, const float* __restrict__ sb,
    const float* __restrict__ g, const float* __restrict__ be,
    float* __restrict__ g4, float* __restrict__ b4)
{
  int i = blockIdx.x * 256 + threadIdx.x;
  if (i < 1536)      { g4[i] = sg[i];      b4[i] = sb[i]; }
  else if (i < 2048) { g4[i] = g[i-1536];  b4[i] = be[i-1536]; }
}

__global__ void row_sumsq_kernel(const float* __restrict__ X, float* __restrict__ out, int nrows)
{
  int row  = blockIdx.x * 4 + (threadIdx.x >> 6);
  int lane = threadIdx.x & 63;
  if (row >= nrows) return;
  const float* p = X + (size_t)row * 512 + lane * 8;
  float4 a = ld4(p), b = ld4(p + 4);
  float s = a.x*a.x + a.y*a.y + a.z*a.z + a.w*a.w
          + b.x*b.x + b.y*b.y + b.z*b.z + b.w*b.w;
  for (int off = 32; off; off >>= 1) s += __shfl_down(s, off, 64);
  if (lane == 0) out[row] = s;
}

// ---------------------------------------------------------------------------
// topk_scan1 / topk_rescue2 / knn_gather — unchanged (R3-verified).
// ---------------------------------------------------------------------------
__global__ __launch_bounds__(256) void topk_scan1_kernel(const float* __restrict__ S,
    const float* __restrict__ qn, const float* __restrict__ kn, int rowbase,
    float2* __restrict__ cand)
{
  const int row  = blockIdx.x;
  const int grow = rowbase + row;
  const int cb   = blockIdx.y;
  const float qnr = qn[grow];
  const float* Srow = S + (size_t)row * 32768 + cb * 8192;
  const float* knb  = kn + cb * 8192;
  const int t = threadIdx.x;
  const float INF = __builtin_inff();

  float vals[6]; int idxs[6];
  #pragma unroll
  for (int j = 0; j < 6; ++j) { vals[j] = INF; idxs[j] = 0x7fffffff; }

  auto ins = [&](float d2, int ci) {
    if (d2 < vals[5] || (d2 == vals[5] && ci < idxs[5])) {
      float cv = d2; int cc = ci;
      #pragma unroll
      for (int j = 0; j < 6; ++j) {
        bool less = (cv < vals[j]) || (cv == vals[j] && cc < idxs[j]);
        float tv = less ? vals[j] : cv; int ti = less ? idxs[j] : cc;
        vals[j] = less ? cv : vals[j]; idxs[j] = less ? cc : idxs[j];
        cv = tv; cc = ti;
      }
    }
  };

  #pragma unroll
  for (int i = 0; i < 8; ++i) {
    int c = (i * 256 + t) * 4;
    float4 s4 = ld4(Srow + c);
    float4 k4 = ld4(knb + c);
    int gcol = cb * 8192 + c;
    ins((qnr + k4.x) - 2.f * s4.x, gcol + 0);
    ins((qnr + k4.y) - 2.f * s4.y, gcol + 1);
    ins((qnr + k4.z) - 2.f * s4.z, gcol + 2);
    ins((qnr + k4.w) - 2.f * s4.w, gcol + 3);
  }

  __shared__ float Wv[4]; __shared__ int Wi[4];
  const int lane = t & 63, wid = t >> 6;
  for (int sel = 0; sel < 16; ++sel) {
    float bv = vals[0]; int bi = idxs[0];
    #pragma unroll
    for (int off = 32; off >= 1; off >>= 1) {
      float ov = __shfl_down(bv, off, 64);
      int   oi = __shfl_down(bi, off, 64);
      if (ov < bv || (ov == bv && oi < bi)) { bv = ov; bi = oi; }
    }
    if (lane == 0) { Wv[wid] = bv; Wi[wid] = bi; }
    __syncthreads();
    float gv = Wv[0]; int gi = Wi[0];
    #pragma unroll
    for (int w2 = 1; w2 < 4; ++w2) {
      float wv2 = Wv[w2]; int wi2 = Wi[w2];
      if (wv2 < gv || (wv2 == gv && wi2 < gi)) { gv = wv2; gi = wi2; }
    }
    if (t == 0) {
      float2 e; e.x = gv; e.y = __int_as_float(gi);
      cand[(size_t)grow * 64 + cb * 16 + sel] = e;
    }
    if (vals[0] == gv && idxs[0] == gi) {
      #pragma unroll
      for (int j = 0; j < 5; ++j) { vals[j] = vals[j+1]; idxs[j] = idxs[j+1]; }
      vals[5] = INF; idxs[5] = 0x7fffffff;
    }
    __syncthreads();
  }
}

__global__ __launch_bounds__(256) void topk_rescue2_kernel(const float2* __restrict__ cand,
    const float* __restrict__ fusedF, const float* __restrict__ queue,
    const float* __restrict__ qn, const float* __restrict__ kn,
    float* __restrict__ topd2, int* __restrict__ topidx)
{
  const int grow = blockIdx.x;
  const int t = threadIdx.x;
  const float INF = __builtin_inff();
  const float qnr = qn[grow];
  __shared__ int Ci[16]; __shared__ float Cd[16];

  if (t < 64) {
    float2 e = cand[(size_t)grow * 64 + t];
    float v = e.x; int id = __float_as_int(e.y);
    for (int sel = 0; sel < 16; ++sel) {
      float bv = v; int bi = id;
      #pragma unroll
      for (int off = 32; off >= 1; off >>= 1) {
        float ov = __shfl_down(bv, off, 64);
        int   oi = __shfl_down(bi, off, 64);
        if (ov < bv || (ov == bv && oi < bi)) { bv = ov; bi = oi; }
      }
      bv = __shfl(bv, 0, 64); bi = __shfl(bi, 0, 64);
      if (t == 0) Ci[sel] = bi;
      if (id == bi) { v = INF; id = 0x7fffffff; }
    }
  }
  __syncthreads();

  {
    int c = t >> 4, s = t & 15;
    int qi = Ci[c];
    const float* qp = queue  + (size_t)qi * 512 + s * 32;
    const float* fp = fusedF + (size_t)grow * 512 + s * 32;
    float dot = 0.f;
    #pragma unroll
    for (int j = 0; j < 8; ++j) {
      float4 a = ld4(fp + j*4); float4 b = ld4(qp + j*4);
      dot += a.x*b.x + a.y*b.y + a.z*b.z + a.w*b.w;
    }
    #pragma unroll
    for (int off = 8; off >= 1; off >>= 1) dot += __shfl_down(dot, off, 16);
    if (s == 0) Cd[c] = qnr + kn[qi] - 2.f * dot;
  }
  __syncthreads();

  if (t < 64) {
    float v = (t < 16) ? Cd[t] : INF;
    int  id = (t < 16) ? Ci[t] : 0x7fffffff;
    for (int sel = 0; sel < TK; ++sel) {
      float bv = v; int bi = id;
      #pragma unroll
      for (int off = 32; off >= 1; off >>= 1) {
        float ov = __shfl_down(bv, off, 64);
        int   oi = __shfl_down(bi, off, 64);
        if (ov < bv || (ov == bv && oi < bi)) { bv = ov; bi = oi; }
      }
      bv = __shfl(bv, 0, 64); bi = __shfl(bi, 0, 64);
      if (t == 0) { topd2[grow*TK + sel] = bv; topidx[grow*TK + sel] = bi; }
      if (id == bi) { v = INF; id = 0x7fffffff; }
    }
  }
}

__global__ void knn_gather_kernel(const float* __restrict__ topd2, const int* __restrict__ topidx,
    const float* __restrict__ queue, float* __restrict__ neigh)
{
  const int row = blockIdx.x;
  const int t = threadIdx.x;   // 64
  __shared__ float ls[TK]; __shared__ float wv[TK]; __shared__ int wid[TK];
  if (t < TK) {
    float d = sqrtf(fmaxf(topd2[row*TK + t], 0.f));
    ls[t]  = -d / 0.07f;
    wid[t] = topidx[row*TK + t];
  }
  __syncthreads();
  if (t < TK) {
    float m = ls[0];
    #pragma unroll
    for (int j = 1; j < TK; ++j) m = fmaxf(m, ls[j]);
    wv[t] = __expf(ls[t] - m);
  }
  __syncthreads();
  float ssum = 0.f;
  #pragma unroll
  for (int j = 0; j < TK; ++j) ssum += wv[j];
  float inv = 1.f / ssum;
  #pragma unroll
  for (int u = 0; u < 8; ++u) {
    int c = u * 64 + t;
    float acc = 0.f;
    #pragma unroll
    for (int k = 0; k < TK; ++k)
      acc = fmaf(wv[k] * inv, queue[(size_t)wid[k] * 512 + c], acc);
    neigh[(size_t)row * 512 + c] = acc;
  }
}

// out[r,c] = b2[c] + sum_k relu(Z[r,k]*sc+sh) * W2[k,c]; head = r>>10.
__global__ void gemm_n18_kernel(const float* __restrict__ Z,
    const float* __restrict__ sc, const float* __restrict__ sh,
    const float* __restrict__ W2, const float* __restrict__ b2,
    float* __restrict__ out, int Mrows)
{
  int o = blockIdx.x * 256 + threadIdx.x;
  if (o >= Mrows * 18) return;
  int r = o / 18, c = o - r * 18;
  const float* zp = Z + (size_t)r * 512;
  const float* scp = sc + (r >> 10) * 512;
  const float* shp = sh + (r >> 10) * 512;
  float acc = b2[c];
  #pragma unroll 8
  for (int k = 0; k < 512; ++k) {
    float z = fmaxf(0.f, fmaf(zp[k], scp[k], shp[k]));
    acc = fmaf(z, W2[k*18 + c], acc);
  }
  out[o] = acc;
}

// ---------------------------------------------------------------------------
extern "C" void kernel_launch(void* const* d_in, const int* in_sizes, int n_in,
                              void* d_out, int out_size, void* d_ws, size_t ws_size,
                              hipStream_t stream)
{
  #define IN(i) ((const float*)d_in[i])
  const float* img_feat = IN(0);
  const float* option   = IN(1);
  const float* semantic = IN(2);
  const float* queue    = IN(3);
  const float* vae_w1 = IN(4);  const float* vae_b1 = IN(5);
  const float* vae_g1 = IN(6);  const float* vae_be1 = IN(7);
  const float* vae_w2 = IN(8);  const float* vae_b2 = IN(9);
  const float* opt_w1 = IN(10); const float* opt_b1 = IN(11);
  const float* opt_g1 = IN(12); const float* opt_be1 = IN(13);
  const float* opt_w2 = IN(14); const float* opt_b2 = IN(15);
  const float* opt_g2 = IN(16); const float* opt_be2 = IN(17);
  const float* sem_w1 = IN(18); const float* sem_b1 = IN(19);
  const float* sem_g1 = IN(20); const float* sem_be1 = IN(21);
  const float* sem_w2 = IN(22); const float* sem_b2 = IN(23);
  const float* sem_g2 = IN(24); const float* sem_be2 = IN(25);
  const float* fus_w = IN(26);  const float* fus_b = IN(27);
  const float* fus_g = IN(28);  const float* fus_be = IN(29);
  const float* fus_sg = IN(30); const float* fus_sb = IN(31);
  const float* cls_w1 = IN(32); const float* cls_b1 = IN(33);
  const float* cls_g = IN(34);  const float* cls_be = IN(35);
  const float* cls_w2 = IN(36); const float* cls_b2 = IN(37);

  float* ws = (float*)d_ws;
  size_t off = 0;
  auto alloc = [&](size_t n) { float* p = ws + off; off += (n + 255) & ~(size_t)255; return p; };

  const int srows = 128;

  float* S    = alloc((size_t)srows * 32768);
  float* H    = alloc(4 * 1024 * 512);
  float* Z4   = alloc(4 * 1024 * 512);
  float* zstart = ws + off;          // ---- zeroed region (split-K atomic outputs)
  float* t1   = alloc(1024 * 512);      // also fusedb (after VAE2 done)
  float* img  = alloc(1024 * 512);
  float* o1p  = alloc(1024 * 256);
  float* optb = alloc(1024 * 512);      // also neigh (after FUS1 done)
  float* s1p  = alloc(1024 * 256);
  float* semb = alloc(1024 * 512);
  float* P    = alloc(3 * 1024 * 512);
  float* Z1   = alloc(1024 * 512);
  size_t zbytes = (size_t)((ws + off) - zstart) * 4;   // ---- end zero region
  // split bf16 transposed weights: alloc(elems) floats == 2*elems u16 (hi||lo)
  u16* vae_w1t = (u16*)alloc(1048576);
  u16* vae_w2t = (u16*)alloc(262144);
  u16* opt_w1t = (u16*)alloc(196608);
  u16* opt_w2t = (u16*)alloc(131072);
  u16* sem_w1t = (u16*)alloc(196608);
  u16* sem_w2t = (u16*)alloc(131072);
  u16* fus0t   = (u16*)alloc(262144);
  u16* fus1t   = (u16*)alloc(262144);
  u16* fus2t   = (u16*)alloc(262144);
  u16* cls_w1t = (u16*)alloc(262144);
  float* qn   = alloc(1024);
  float* kn   = alloc(32768);
  float2* cand = (float2*)alloc(1024 * 64 * 2);
  float* scv  = alloc(512);  float* shv  = alloc(512);
  float* sco1 = alloc(256);  float* sho1 = alloc(256);
  float* sco2 = alloc(512);  float* sho2 = alloc(512);
  float* scs1 = alloc(256);  float* shs1 = alloc(256);
  float* scs2 = alloc(512);  float* shs2 = alloc(512);
  float* scf  = alloc(4*512); float* shf = alloc(4*512);
  float* scc4 = alloc(4*512); float* shc4 = alloc(4*512);
  float* scc1 = alloc(512);  float* shc1 = alloc(512);
  float* g4   = alloc(4*512); float* b4  = alloc(4*512);
  float* topd2 = alloc(1024 * TK);
  int*   topidx = (int*)alloc(1024 * TK);

  float* fusedb = t1;
  float* neigh  = optb;

  dim3 blk(256);

  // --- weight transpose+pack (one launch, split hi/lo) ---
  TDs ds;
  ds.d[0] = { vae_w1, vae_w1t, 2048, 2048, 512, 512 };
  ds.d[1] = { vae_w2, vae_w2t,  512,  512, 512, 512 };
  ds.d[2] = { opt_w1, opt_w1t,  768,  768, 192, 256 };
  ds.d[3] = { opt_w2, opt_w2t,  192,  256, 512, 512 };
  ds.d[4] = { sem_w1, sem_w1t,  768,  768, 192, 256 };
  ds.d[5] = { sem_w2, sem_w2t,  192,  256, 512, 512 };
  ds.d[6] = { fus_w,            fus0t, 512, 512, 512, 512 };
  ds.d[7] = { fus_w + 262144,   fus1t, 512, 512, 512, 512 };
  ds.d[8] = { fus_w + 524288,   fus2t, 512, 512, 512, 512 };
  ds.d[9] = { cls_w1, cls_w1t,  512,  512, 512, 512 };
  wt_transpose_kernel<<<dim3(256, 10), blk, 0, stream>>>(ds);
  hipMemsetAsync(zstart, 0, zbytes, stream);

  // --- VAE: t1 = img_feat@W1+b1; img = relu(bn(t1))@W2+b2 (BN fused in staging)
  gemm_bt_mfma_kernel<<<dim3(4,8,8), blk, 0, stream>>>(img_feat, vae_w1t, 1048576, vae_b1, 512, nullptr, nullptr, 0, t1, 512, 2048);
  bn_stats_kernel<<<dim3(8,1), dim3(1024), 0, stream>>>(t1, 512, vae_g1, vae_be1, 0, 512, scv, shv);
  gemm_bt_mfma_kernel<<<dim3(4,8,4), blk, 0, stream>>>(t1, vae_w2t, 262144, vae_b2, 512, scv, shv, 0, img, 512, 512);
  // --- option encoder
  gemm_bt_mfma_kernel<<<dim3(2,8,8), blk, 0, stream>>>(option, opt_w1t, 196608, opt_b1, 192, nullptr, nullptr, 0, o1p, 256, 768);
  bn_stats_kernel<<<dim3(4,1), dim3(1024), 0, stream>>>(o1p, 256, opt_g1, opt_be1, 0, 192, sco1, sho1);
  gemm_bt_mfma_kernel<<<dim3(4,8,4), blk, 0, stream>>>(o1p, opt_w2t, 131072, opt_b2, 512, sco1, sho1, 0, optb, 512, 256);
  bn_stats_kernel<<<dim3(8,1), dim3(1024), 0, stream>>>(optb, 512, opt_g2, opt_be2, 0, 512, sco2, sho2);
  // --- semantic encoder
  gemm_bt_mfma_kernel<<<dim3(2,8,8), blk, 0, stream>>>(semantic, sem_w1t, 196608, sem_b1, 192, nullptr, nullptr, 0, s1p, 256, 768);
  bn_stats_kernel<<<dim3(4,1), dim3(1024), 0, stream>>>(s1p, 256, sem_g1, sem_be1, 0, 192, scs1, shs1);
  gemm_bt_mfma_kernel<<<dim3(4,8,4), blk, 0, stream>>>(s1p, sem_w2t, 131072, sem_b2, 512, scs1, shs1, 0, semb, 512, 256);
  bn_stats_kernel<<<dim3(8,1), dim3(1024), 0, stream>>>(semb, 512, sem_g2, sem_be2, 0, 512, scs2, shs2);
  // --- fusion partials (BN of optb/semb fused into staging)
  gemm_bt_mfma_kernel<<<dim3(4,8,4), blk, 0, stream>>>(img,  fus0t, 262144, nullptr, 0, nullptr, nullptr, 0, P,           512, 512);
  gemm_bt_mfma_kernel<<<dim3(4,8,4), blk, 0, stream>>>(optb, fus1t, 262144, nullptr, 0, sco2, sho2, 0, P + 524288,  512, 512);
  gemm_bt_mfma_kernel<<<dim3(4,8,4), blk, 0, stream>>>(semb, fus2t, 262144, nullptr, 0, scs2, shs2, 0, P + 1048576, 512, 512);
  fuse_combine_kernel<<<dim3(512), blk, 0, stream>>>(P, fus_w + 1536*512, fus_b, H);
  pack_gb_kernel<<<dim3(8), blk, 0, stream>>>(fus_sg, fus_sb, fus_g, fus_be, g4, b4);
  bn_stats_kernel<<<dim3(8,4), dim3(1024), 0, stream>>>(H, 512, g4, b4, 512, 512, scf, shf);
  bn_apply512_kernel<<<dim3(512), blk, 0, stream>>>(fusedb, H + (size_t)3*1024*512, scf + 1536, shf + 1536);
  // --- classifier heads 0..3 (M=4096 -> 128 blocks natively, no split-K)
  gemm_bt_mfma_kernel<<<dim3(4,32,1), blk, 0, stream>>>(H, cls_w1t, 262144, cls_b1, 512, scf, shf, 1, Z4, 512, 512);
  bn_stats_kernel<<<dim3(8,4), dim3(1024), 0, stream>>>(Z4, 512, cls_g, cls_be, 0, 512, scc4, shc4);
  gemm_n18_kernel<<<dim3(288), blk, 0, stream>>>(Z4, scc4, shc4, cls_w2, cls_b2, (float*)d_out, 4096);
  // --- kNN retrieval
  row_sumsq_kernel<<<dim3(256), blk, 0, stream>>>(fusedb, qn, 1024);
  row_sumsq_kernel<<<dim3(8192), blk, 0, stream>>>(queue, kn, 32768);
  for (int sbase = 0; sbase < 1024; sbase += srows) {
    score_mfma_kernel<<<dim3(256, srows/128), blk, 0, stream>>>(fusedb + (size_t)sbase*512, queue, S);
    topk_scan1_kernel<<<dim3(srows, 4), blk, 0, stream>>>(S, qn, kn, sbase, cand);
  }
  topk_rescue2_kernel<<<dim3(1024), blk, 0, stream>>>(cand, fusedb, queue, qn, kn, topd2, topidx);
  knn_gather_kernel<<<dim3(1024), dim3(64), 0, stream>>>(topd2, topidx, queue, neigh);
  // --- classifier head 4
  gemm_bt_mfma_kernel<<<dim3(4,8,4), blk, 0, stream>>>(neigh, cls_w1t, 262144, cls_b1, 512, nullptr, nullptr, 0, Z1, 512, 512);
  bn_stats_kernel<<<dim3(8,1), dim3(1024), 0, stream>>>(Z1, 512, cls_g, cls_be, 0, 512, scc1, shc1);
  gemm_n18_kernel<<<dim3(72), blk, 0, stream>>>(Z1, scc1, shc1, cls_w2, cls_b2, (float*)d_out + 4*1024*18, 1024);
  #undef IN
}

// Round 8
// 941.995 us; speedup vs baseline: 1.3174x; 1.1404x over previous
//
#include <hip/hip_runtime.h>
#include <cstdint>
#include <cstddef>

#define TK 10

typedef unsigned short u16;
typedef __attribute__((ext_vector_type(8))) short short8;
typedef __attribute__((ext_vector_type(4))) float f32x4;

__device__ __forceinline__ float4 ld4(const float* p){ return *(const float4*)p; }

__device__ __forceinline__ u16 bfr(float x){
  unsigned u = __float_as_uint(x);
  return (u16)((u + 0x7FFFu + ((u >> 16) & 1u)) >> 16);
}
__device__ __forceinline__ float b2f(u16 h){
  unsigned u = ((unsigned)h) << 16;
  return __uint_as_float(u);
}

// ---------------------------------------------------------------------------
// wt_transpose: packs weights W[K,N] fp32 -> Wt[Np,Kp] (transposed, padded)
// as SPLIT bf16: hi at [0, Np*Kp), lo at [Np*Kp, 2*Np*Kp).
// ---------------------------------------------------------------------------
struct TD { const float* W; u16* Wt; int K, Kp, N, Np; };
struct TDs { TD d[10]; };

__global__ __launch_bounds__(256) void wt_transpose_kernel(TDs ds)
{
  TD d = ds.d[blockIdx.y];
  const size_t loOff = (size_t)d.Np * d.Kp;
  const int tilesN = d.Np >> 6;
  const int tiles  = (d.Kp >> 6) * tilesN;
  const int tid = blockIdx.x;
  if (tid >= tiles) return;
  const int k0 = (tid / tilesN) << 6, n0 = (tid % tilesN) << 6;
  const int t = threadIdx.x, tc = t & 63, tr = t >> 6;
  __shared__ float L[64][65];
  const bool have = (k0 < d.K) && (n0 < d.N);
  if (have) {
    #pragma unroll
    for (int i = 0; i < 16; ++i) {
      int kk = tr + i * 4;
      L[kk][tc] = d.W[(size_t)(k0 + kk) * d.N + n0 + tc];
    }
  }
  __syncthreads();
  #pragma unroll
  for (int i = 0; i < 16; ++i) {
    int nn = tr + i * 4;
    u16 hi = 0, lo = 0;
    if (have) {
      float v = L[tc][nn];
      hi = bfr(v);
      lo = bfr(v - b2f(hi));
    }
    size_t idx = (size_t)(n0 + nn) * d.Kp + k0 + tc;
    d.Wt[idx] = hi;
    d.Wt[loOff + idx] = lo;
  }
}

// ---------------------------------------------------------------------------
// gemm_bt_mfma v3: split-bf16 3-term, 64x128 tile (MxN), BK=32, double-buffer.
// Per-head (head = m0>>10, M per head = 1024): weights Bw + head*wstride
// (lo at +loOff within block), asc/ash at head*K. z>1: plain-store partials
// to C + z*M*N (reduce_bias sums + bias afterwards). z==1: direct + bias.
// ---------------------------------------------------------------------------
__global__ __launch_bounds__(256) void gemm_bt_mfma_kernel(
    const float* __restrict__ A, const u16* __restrict__ Bw,
    size_t loOff, size_t wstride,
    const float* __restrict__ bias, int biasN,
    const float* __restrict__ asc, const float* __restrict__ ash, int headed,
    float* __restrict__ C, int M, int N, int K)
{
  __shared__ u16 AhL[2][64*32], AlL[2][64*32], BhL[2][128*32], BlL[2][128*32];
  const int t  = threadIdx.x;
  const int n0 = blockIdx.x * 128;
  const int m0 = blockIdx.y * 64;
  const int head = headed ? (m0 >> 10) : 0;
  const u16* Bws = Bw + (size_t)head * wstride;
  const int kchunk = K / gridDim.z;
  const int kbeg = blockIdx.z * kchunk;
  const int iters = kchunk >> 5;

  // A staging: 64 rows x 4 chunks(8 elem) = 256 chunks, 1/thread
  const int aRow = t >> 2, aC = t & 3;
  const int aPhys = (aRow * 4 + (aC ^ (aRow & 3))) * 8;
  const float* gA = A + (size_t)(m0 + aRow) * K + kbeg + aC * 8;
  const int colcA = head * K + kbeg + aC * 8;
  // B staging: 128 rows x 4 chunks = 512 chunks, 2/thread
  int bPhys[2]; const u16* gBh[2]; const u16* gBl[2];
  #pragma unroll
  for (int i = 0; i < 2; ++i) {
    int L = i * 256 + t;
    int row = L >> 2, c = L & 3;
    bPhys[i] = (row * 4 + (c ^ (row & 3))) * 8;
    gBh[i] = Bws + (size_t)(n0 + row) * K + kbeg + c * 8;
    gBl[i] = gBh[i] + loOff;
  }

  const int lane = t & 63, w = t >> 6;
  const int wm = (w >> 1) * 32, wn = (w & 1) * 64;
  const int q = lane >> 4, rl = lane & 15;

  f32x4 acc[2][4];
  const f32x4 z4 = {0.f, 0.f, 0.f, 0.f};
  #pragma unroll
  for (int i = 0; i < 2; ++i)
    #pragma unroll
    for (int j = 0; j < 4; ++j) acc[i][j] = z4;

  union U16x8 { u16 u[8]; float4 f4; };
  float ra[8]; uint4 rbh[2], rbl[2];

  auto prefetch = [&](int it) {
    const float* pa = gA + it * 32;
    float4 a0 = ld4(pa), a1 = ld4(pa + 4);
    ra[0]=a0.x; ra[1]=a0.y; ra[2]=a0.z; ra[3]=a0.w;
    ra[4]=a1.x; ra[5]=a1.y; ra[6]=a1.z; ra[7]=a1.w;
    #pragma unroll
    for (int i = 0; i < 2; ++i) {
      rbh[i] = *(const uint4*)(gBh[i] + it * 32);
      rbl[i] = *(const uint4*)(gBl[i] + it * 32);
    }
    if (asc) {
      int j0 = colcA + it * 32;
      #pragma unroll
      for (int j = 0; j < 8; ++j)
        ra[j] = fmaxf(0.f, fmaf(ra[j], asc[j0 + j], ash[j0 + j]));
    }
  };
  auto stage = [&](int buf) {
    U16x8 ph, pl;
    #pragma unroll
    for (int j = 0; j < 8; ++j) {
      u16 h = bfr(ra[j]);
      ph.u[j] = h;
      pl.u[j] = bfr(ra[j] - b2f(h));
    }
    *(float4*)&AhL[buf][aPhys] = ph.f4;
    *(float4*)&AlL[buf][aPhys] = pl.f4;
    #pragma unroll
    for (int i = 0; i < 2; ++i) {
      *(uint4*)&BhL[buf][bPhys[i]] = rbh[i];
      *(uint4*)&BlL[buf][bPhys[i]] = rbl[i];
    }
  };
  auto compute = [&](int buf) {
    short8 afh[2], afl[2], bfh[4], bfl[4];
    #pragma unroll
    for (int mt = 0; mt < 2; ++mt) {
      int r = wm + mt * 16 + rl;
      int cc = q ^ (r & 3);
      afh[mt] = *(const short8*)&AhL[buf][(r * 4 + cc) * 8];
      afl[mt] = *(const short8*)&AlL[buf][(r * 4 + cc) * 8];
    }
    #pragma unroll
    for (int nt = 0; nt < 4; ++nt) {
      int r = wn + nt * 16 + rl;
      int cc = q ^ (r & 3);
      bfh[nt] = *(const short8*)&BhL[buf][(r * 4 + cc) * 8];
      bfl[nt] = *(const short8*)&BlL[buf][(r * 4 + cc) * 8];
    }
    #pragma unroll
    for (int mt = 0; mt < 2; ++mt)
      #pragma unroll
      for (int nt = 0; nt < 4; ++nt) {
        acc[mt][nt] = __builtin_amdgcn_mfma_f32_16x16x32_bf16(afl[mt], bfh[nt], acc[mt][nt], 0, 0, 0);
        acc[mt][nt] = __builtin_amdgcn_mfma_f32_16x16x32_bf16(afh[mt], bfl[nt], acc[mt][nt], 0, 0, 0);
        acc[mt][nt] = __builtin_amdgcn_mfma_f32_16x16x32_bf16(afh[mt], bfh[nt], acc[mt][nt], 0, 0, 0);
      }
  };

  prefetch(0);
  stage(0);
  __syncthreads();
  int buf = 0;
  for (int it = 0; it < iters; ++it) {
    if (it + 1 < iters) prefetch(it + 1);
    compute(buf);
    if (it + 1 < iters) { stage(buf ^ 1); __syncthreads(); buf ^= 1; }
  }

  // epilogue: C/D layout col = lane&15, row = q*4 + reg  [m89-verified]
  if (gridDim.z == 1) {
    #pragma unroll
    for (int nt = 0; nt < 4; ++nt) {
      int n = n0 + wn + nt * 16 + rl;
      float bv = (bias && n < biasN) ? bias[n] : 0.f;
      #pragma unroll
      for (int mt = 0; mt < 2; ++mt) {
        int m = m0 + wm + mt * 16 + q * 4;
        #pragma unroll
        for (int reg = 0; reg < 4; ++reg)
          C[(size_t)(m + reg) * N + n] = acc[mt][nt][reg] + bv;
      }
    }
  } else {
    float* Cz = C + (size_t)blockIdx.z * M * N;
    #pragma unroll
    for (int nt = 0; nt < 4; ++nt) {
      int n = n0 + wn + nt * 16 + rl;
      #pragma unroll
      for (int mt = 0; mt < 2; ++mt) {
        int m = m0 + wm + mt * 16 + q * 4;
        #pragma unroll
        for (int reg = 0; reg < 4; ++reg)
          Cz[(size_t)(m + reg) * N + n] = acc[mt][nt][reg];
      }
    }
  }
}

// C[i] = sum_z Cp[z][i] + bias; headedBias: bias idx = (row>>10)*N + col.
__global__ void reduce_bias_kernel(const float* __restrict__ Cp, size_t slice, int z,
    const float* __restrict__ bias, int biasN, int headedBias,
    float* __restrict__ C, int N, int total4)
{
  int i = blockIdx.x * 256 + threadIdx.x;
  if (i >= total4) return;
  size_t base = (size_t)i * 4;
  float4 s = ld4(Cp + base);
  for (int zz = 1; zz < z; ++zz) {
    float4 v = ld4(Cp + (size_t)zz * slice + base);
    s.x += v.x; s.y += v.y; s.z += v.z; s.w += v.w;
  }
  if (bias) {
    int col = (int)(base % (size_t)N);
    int boff = headedBias ? (int)(base / ((size_t)1024 * N)) * N : 0;
    if (col + 0 < biasN) s.x += bias[boff + col + 0];
    if (col + 1 < biasN) s.y += bias[boff + col + 1];
    if (col + 2 < biasN) s.z += bias[boff + col + 2];
    if (col + 3 < biasN) s.w += bias[boff + col + 3];
  }
  *(float4*)&C[base] = s;
}

__global__ void pack3_kernel(const float* __restrict__ a, const float* __restrict__ b,
    const float* __restrict__ c, float* __restrict__ dst, int n)
{
  int i = blockIdx.x * 256 + threadIdx.x;
  if (i < n) dst[i] = a[i];
  else if (i < 2*n) dst[i] = b[i - n];
  else if (i < 3*n) dst[i] = c[i - 2*n];
}

// ---------------------------------------------------------------------------
// score_mfma: approx scores, single bf16 (selection only; rescue is exact).
// ---------------------------------------------------------------------------
__global__ __launch_bounds__(256) void score_mfma_kernel(
    const float* __restrict__ A, const float* __restrict__ Bq,
    float* __restrict__ C)
{
  __shared__ u16 At[128 * 64];
  __shared__ u16 Bt[128 * 64];
  const int t  = threadIdx.x;
  const int n0 = blockIdx.x * 128;
  const int m0 = blockIdx.y * 128;

  u16* ldsA[4]; u16* ldsB[4];
  const float* gA[4]; const float* gB[4];
  #pragma unroll
  for (int i = 0; i < 4; ++i) {
    int L = i * 256 + t;
    int row = L >> 3, c = L & 7;
    int phys = row * 8 + (c ^ (row & 7));
    ldsA[i] = &At[phys * 8]; ldsB[i] = &Bt[phys * 8];
    gA[i] = A  + (size_t)(m0 + row) * 512 + c * 8;
    gB[i] = Bq + (size_t)(n0 + row) * 512 + c * 8;
  }

  const int lane = t & 63, w = t >> 6;
  const int wm = (w >> 1) * 64, wn = (w & 1) * 64;
  const int q = lane >> 4, rl = lane & 15;

  f32x4 acc[4][4];
  const f32x4 z4 = {0.f, 0.f, 0.f, 0.f};
  #pragma unroll
  for (int i = 0; i < 4; ++i)
    #pragma unroll
    for (int j = 0; j < 4; ++j) acc[i][j] = z4;

  union U16x8 { u16 u[8]; float4 f4; };

  for (int k0 = 0; k0 < 512; k0 += 64) {
    float4 ra[4][2], rb[4][2];
    #pragma unroll
    for (int i = 0; i < 4; ++i) {
      ra[i][0] = ld4(gA[i]); ra[i][1] = ld4(gA[i] + 4);
      rb[i][0] = ld4(gB[i]); rb[i][1] = ld4(gB[i] + 4);
      gA[i] += 64; gB[i] += 64;
    }
    __syncthreads();
    #pragma unroll
    for (int i = 0; i < 4; ++i) {
      U16x8 pa, pb;
      pa.u[0]=bfr(ra[i][0].x); pa.u[1]=bfr(ra[i][0].y); pa.u[2]=bfr(ra[i][0].z); pa.u[3]=bfr(ra[i][0].w);
      pa.u[4]=bfr(ra[i][1].x); pa.u[5]=bfr(ra[i][1].y); pa.u[6]=bfr(ra[i][1].z); pa.u[7]=bfr(ra[i][1].w);
      pb.u[0]=bfr(rb[i][0].x); pb.u[1]=bfr(rb[i][0].y); pb.u[2]=bfr(rb[i][0].z); pb.u[3]=bfr(rb[i][0].w);
      pb.u[4]=bfr(rb[i][1].x); pb.u[5]=bfr(rb[i][1].y); pb.u[6]=bfr(rb[i][1].z); pb.u[7]=bfr(rb[i][1].w);
      *(float4*)ldsA[i] = pa.f4;
      *(float4*)ldsB[i] = pb.f4;
    }
    __syncthreads();
    #pragma unroll
    for (int kk = 0; kk < 2; ++kk) {
      short8 af[4], bfv[4];
      #pragma unroll
      for (int mt = 0; mt < 4; ++mt) {
        int r = wm + mt * 16 + rl;
        int cc = (kk * 4 + q) ^ (r & 7);
        af[mt] = *(const short8*)&At[(r * 8 + cc) * 8];
      }
      #pragma unroll
      for (int nt = 0; nt < 4; ++nt) {
        int r = wn + nt * 16 + rl;
        int cc = (kk * 4 + q) ^ (r & 7);
        bfv[nt] = *(const short8*)&Bt[(r * 8 + cc) * 8];
      }
      #pragma unroll
      for (int mt = 0; mt < 4; ++mt)
        #pragma unroll
        for (int nt = 0; nt < 4; ++nt)
          acc[mt][nt] = __builtin_amdgcn_mfma_f32_16x16x32_bf16(af[mt], bfv[nt], acc[mt][nt], 0, 0, 0);
    }
  }
  #pragma unroll
  for (int mt = 0; mt < 4; ++mt)
    #pragma unroll
    for (int nt = 0; nt < 4; ++nt) {
      int m = m0 + wm + mt * 16 + q * 4;
      int n = n0 + wn + nt * 16 + rl;
      #pragma unroll
      for (int reg = 0; reg < 4; ++reg)
        C[(size_t)(m + reg) * 32768 + n] = acc[mt][nt][reg];
    }
}

// ---------------------------------------------------------------------------
// BN column stats over 1024 rows -> scale/shift.
// ---------------------------------------------------------------------------
__global__ __launch_bounds__(1024) void bn_stats_kernel(const float* __restrict__ X, int N,
    const float* __restrict__ gamma, const float* __restrict__ beta, int gstride, int gN,
    float* __restrict__ scale, float* __restrict__ shift)
{
  const int head = blockIdx.y;
  const float* Xh = X + (size_t)head * 1024 * N;
  const int lane = threadIdx.x & 63;
  const int col  = blockIdx.x * 64 + lane;
  const int rg   = threadIdx.x >> 6;
  float s = 0.f, ss = 0.f;
  const float* p = Xh + (size_t)(rg * 64) * N + col;
  for (int rr = 0; rr < 64; ++rr) { float v = *p; p += N; s += v; ss = fmaf(v, v, ss); }
  __shared__ float Ssum[16][64], Ssq[16][64];
  Ssum[rg][lane] = s; Ssq[rg][lane] = ss;
  __syncthreads();
  if (threadIdx.x < 64) {
    s = 0.f; ss = 0.f;
    #pragma unroll
    for (int r = 0; r < 16; ++r) { s += Ssum[r][lane]; ss += Ssq[r][lane]; }
    float mean = s * (1.f / 1024.f);
    float var  = ss * (1.f / 1024.f) - mean * mean;
    float sc = 0.f, sh = 0.f;
    if (col < gN) {
      sc = gamma[head * gstride + col] / sqrtf(var + 1e-5f);
      sh = beta[head * gstride + col] - mean * sc;
    }
    scale[head * N + col] = sc;
    shift[head * N + col] = sh;
  }
}

// BN+ReLU on a 1024x512 slab (in- or out-of-place)
__global__ void bn_apply512_kernel(float* __restrict__ dst, const float* __restrict__ src,
    const float* __restrict__ scale, const float* __restrict__ shift)
{
  int i = blockIdx.x * 256 + threadIdx.x;
  if (i >= 131072) return;
  size_t base = (size_t)i * 4;
  int col = (int)(base & 511);
  float4 v = ld4(src + base);
  v.x = fmaxf(0.f, fmaf(v.x, scale[col+0], shift[col+0]));
  v.y = fmaxf(0.f, fmaf(v.y, scale[col+1], shift[col+1]));
  v.z = fmaxf(0.f, fmaf(v.z, scale[col+2], shift[col+2]));
  v.w = fmaxf(0.f, fmaf(v.w, scale[col+3], shift[col+3]));
  *(float4*)&dst[base] = v;
}

__global__ void fuse_combine_kernel(const float* __restrict__ P,
    const float* __restrict__ fwr, const float* __restrict__ fb, float* __restrict__ H)
{
  int i = blockIdx.x * 256 + threadIdx.x;
  if (i >= 131072) return;
  size_t base = (size_t)i * 4;
  int c = (int)(base & 511);
  float4 p0 = ld4(P + base), p1 = ld4(P + 524288 + base), p2 = ld4(P + 1048576 + base);
  float4 w0 = ld4(fwr + c), w1 = ld4(fwr + 512 + c), w2 = ld4(fwr + 1024 + c), b = ld4(fb + c);
  float4 h0, h1, h2, h3;
  h0.x=p0.x+w0.x+b.x; h0.y=p0.y+w0.y+b.y; h0.z=p0.z+w0.z+b.z; h0.w=p0.w+w0.w+b.w;
  h1.x=p1.x+w1.x+b.x; h1.y=p1.y+w1.y+b.y; h1.z=p1.z+w1.z+b.z; h1.w=p1.w+w1.w+b.w;
  h2.x=p2.x+w2.x+b.x; h2.y=p2.y+w2.y+b.y; h2.z=p2.z+w2.z+b.z; h2.w=p2.w+w2.w+b.w;
  h3.x=p0.x+p1.x+p2.x+w0.x+w1.x+w2.x+b.x;
  h3.y=p0.y+p1.y+p2.y+w0.y+w1.y+w2.y+b.y;
  h3.z=p0.z+p1.z+p2.z+w0.z+w1.z+w2.z+b.z;
  h3.w=p0.w+p1.w+p2.w+w0.w+w1.w+w2.w+b.w;
  *(float4*)&H[base]           = h0;
  *(float4*)&H[524288 + base]  = h1;
  *(float4*)&H[1048576 + base] = h2;
  *(float4*)&H[1572864 + base] = h3;
}

__global__ void pack_gb_kernel(const float* __restrict__ sg, const float* __restrict__ sb,
    const float* __restrict__ g, const float* __restrict__ be,
    float* __restrict__ g4, float* __restrict__ b4)
{
  int i = blockIdx.x * 256 + threadIdx.x;
  if (i < 1536)      { g4[i] = sg[i];      b4[i] = sb[i]; }
  else if (i < 2048) { g4[i] = g[i-1536];  b4[i] = be[i-1536]; }
}

__global__ void row_sumsq_kernel(const float* __restrict__ X, float* __restrict__ out, int nrows)
{
  int row  = blockIdx.x * 4 + (threadIdx.x >> 6);
  int lane = threadIdx.x & 63;
  if (row >= nrows) return;
  const float* p = X + (size_t)row * 512 + lane * 8;
  float4 a = ld4(p), b = ld4(p + 4);
  float s = a.x*a.x + a.y*a.y + a.z*a.z + a.w*a.w
          + b.x*b.x + b.y*b.y + b.z*b.z + b.w*b.w;
  for (int off = 32; off; off >>= 1) s += __shfl_down(s, off, 64);
  if (lane == 0) out[row] = s;
}

// ---------------------------------------------------------------------------
// topk_scan1 / topk_rescue2 / knn_gather — unchanged (R3-verified).
// ---------------------------------------------------------------------------
__global__ __launch_bounds__(256) void topk_scan1_kernel(const float* __restrict__ S,
    const float* __restrict__ qn, const float* __restrict__ kn, int rowbase,
    float2* __restrict__ cand)
{
  const int row  = blockIdx.x;
  const int grow = rowbase + row;
  const int cb   = blockIdx.y;
  const float qnr = qn[grow];
  const float* Srow = S + (size_t)row * 32768 + cb * 8192;
  const float* knb  = kn + cb * 8192;
  const int t = threadIdx.x;
  const float INF = __builtin_inff();

  float vals[6]; int idxs[6];
  #pragma unroll
  for (int j = 0; j < 6; ++j) { vals[j] = INF; idxs[j] = 0x7fffffff; }

  auto ins = [&](float d2, int ci) {
    if (d2 < vals[5] || (d2 == vals[5] && ci < idxs[5])) {
      float cv = d2; int cc = ci;
      #pragma unroll
      for (int j = 0; j < 6; ++j) {
        bool less = (cv < vals[j]) || (cv == vals[j] && cc < idxs[j]);
        float tv = less ? vals[j] : cv; int ti = less ? idxs[j] : cc;
        vals[j] = less ? cv : vals[j]; idxs[j] = less ? cc : idxs[j];
        cv = tv; cc = ti;
      }
    }
  };

  #pragma unroll
  for (int i = 0; i < 8; ++i) {
    int c = (i * 256 + t) * 4;
    float4 s4 = ld4(Srow + c);
    float4 k4 = ld4(knb + c);
    int gcol = cb * 8192 + c;
    ins((qnr + k4.x) - 2.f * s4.x, gcol + 0);
    ins((qnr + k4.y) - 2.f * s4.y, gcol + 1);
    ins((qnr + k4.z) - 2.f * s4.z, gcol + 2);
    ins((qnr + k4.w) - 2.f * s4.w, gcol + 3);
  }

  __shared__ float Wv[4]; __shared__ int Wi[4];
  const int lane = t & 63, wid = t >> 6;
  for (int sel = 0; sel < 16; ++sel) {
    float bv = vals[0]; int bi = idxs[0];
    #pragma unroll
    for (int off = 32; off >= 1; off >>= 1) {
      float ov = __shfl_down(bv, off, 64);
      int   oi = __shfl_down(bi, off, 64);
      if (ov < bv || (ov == bv && oi < bi)) { bv = ov; bi = oi; }
    }
    if (lane == 0) { Wv[wid] = bv; Wi[wid] = bi; }
    __syncthreads();
    float gv = Wv[0]; int gi = Wi[0];
    #pragma unroll
    for (int w2 = 1; w2 < 4; ++w2) {
      float wv2 = Wv[w2]; int wi2 = Wi[w2];
      if (wv2 < gv || (wv2 == gv && wi2 < gi)) { gv = wv2; gi = wi2; }
    }
    if (t == 0) {
      float2 e; e.x = gv; e.y = __int_as_float(gi);
      cand[(size_t)grow * 64 + cb * 16 + sel] = e;
    }
    if (vals[0] == gv && idxs[0] == gi) {
      #pragma unroll
      for (int j = 0; j < 5; ++j) { vals[j] = vals[j+1]; idxs[j] = idxs[j+1]; }
      vals[5] = INF; idxs[5] = 0x7fffffff;
    }
    __syncthreads();
  }
}

__global__ __launch_bounds__(256) void topk_rescue2_kernel(const float2* __restrict__ cand,
    const float* __restrict__ fusedF, const float* __restrict__ queue,
    const float* __restrict__ qn, const float* __restrict__ kn,
    float* __restrict__ topd2, int* __restrict__ topidx)
{
  const int grow = blockIdx.x;
  const int t = threadIdx.x;
  const float INF = __builtin_inff();
  const float qnr = qn[grow];
  __shared__ int Ci[16]; __shared__ float Cd[16];

  if (t < 64) {
    float2 e = cand[(size_t)grow * 64 + t];
    float v = e.x; int id = __float_as_int(e.y);
    for (int sel = 0; sel < 16; ++sel) {
      float bv = v; int bi = id;
      #pragma unroll
      for (int off = 32; off >= 1; off >>= 1) {
        float ov = __shfl_down(bv, off, 64);
        int   oi = __shfl_down(bi, off, 64);
        if (ov < bv || (ov == bv && oi < bi)) { bv = ov; bi = oi; }
      }
      bv = __shfl(bv, 0, 64); bi = __shfl(bi, 0, 64);
      if (t == 0) Ci[sel] = bi;
      if (id == bi) { v = INF; id = 0x7fffffff; }
    }
  }
  __syncthreads();

  {
    int c = t >> 4, s = t & 15;
    int qi = Ci[c];
    const float* qp = queue  + (size_t)qi * 512 + s * 32;
    const float* fp = fusedF + (size_t)grow * 512 + s * 32;
    float dot = 0.f;
    #pragma unroll
    for (int j = 0; j < 8; ++j) {
      float4 a = ld4(fp + j*4); float4 b = ld4(qp + j*4);
      dot += a.x*b.x + a.y*b.y + a.z*b.z + a.w*b.w;
    }
    #pragma unroll
    for (int off = 8; off >= 1; off >>= 1) dot += __shfl_down(dot, off, 16);
    if (s == 0) Cd[c] = qnr + kn[qi] - 2.f * dot;
  }
  __syncthreads();

  if (t < 64) {
    float v = (t < 16) ? Cd[t] : INF;
    int  id = (t < 16) ? Ci[t] : 0x7fffffff;
    for (int sel = 0; sel < TK; ++sel) {
      float bv = v; int bi = id;
      #pragma unroll
      for (int off = 32; off >= 1; off >>= 1) {
        float ov = __shfl_down(bv, off, 64);
        int   oi = __shfl_down(bi, off, 64);
        if (ov < bv || (ov == bv && oi < bi)) { bv = ov; bi = oi; }
      }
      bv = __shfl(bv, 0, 64); bi = __shfl(bi, 0, 64);
      if (t == 0) { topd2[grow*TK + sel] = bv; topidx[grow*TK + sel] = bi; }
      if (id == bi) { v = INF; id = 0x7fffffff; }
    }
  }
}

__global__ void knn_gather_kernel(const float* __restrict__ topd2, const int* __restrict__ topidx,
    const float* __restrict__ queue, float* __restrict__ neigh)
{
  const int row = blockIdx.x;
  const int t = threadIdx.x;   // 64
  __shared__ float ls[TK]; __shared__ float wv[TK]; __shared__ int wid[TK];
  if (t < TK) {
    float d = sqrtf(fmaxf(topd2[row*TK + t], 0.f));
    ls[t]  = -d / 0.07f;
    wid[t] = topidx[row*TK + t];
  }
  __syncthreads();
  if (t < TK) {
    float m = ls[0];
    #pragma unroll
    for (int j = 1; j < TK; ++j) m = fmaxf(m, ls[j]);
    wv[t] = __expf(ls[t] - m);
  }
  __syncthreads();
  float ssum = 0.f;
  #pragma unroll
  for (int j = 0; j < TK; ++j) ssum += wv[j];
  float inv = 1.f / ssum;
  #pragma unroll
  for (int u = 0; u < 8; ++u) {
    int c = u * 64 + t;
    float acc = 0.f;
    #pragma unroll
    for (int k = 0; k < TK; ++k)
      acc = fmaf(wv[k] * inv, queue[(size_t)wid[k] * 512 + c], acc);
    neigh[(size_t)row * 512 + c] = acc;
  }
}

__global__ void gemm_n18_kernel(const float* __restrict__ Z,
    const float* __restrict__ sc, const float* __restrict__ sh,
    const float* __restrict__ W2, const float* __restrict__ b2,
    float* __restrict__ out, int Mrows)
{
  int o = blockIdx.x * 256 + threadIdx.x;
  if (o >= Mrows * 18) return;
  int r = o / 18, c = o - r * 18;
  const float* zp = Z + (size_t)r * 512;
  const float* scp = sc + (r >> 10) * 512;
  const float* shp = sh + (r >> 10) * 512;
  float acc = b2[c];
  #pragma unroll 8
  for (int k = 0; k < 512; ++k) {
    float z = fmaxf(0.f, fmaf(zp[k], scp[k], shp[k]));
    acc = fmaf(z, W2[k*18 + c], acc);
  }
  out[o] = acc;
}

// ---------------------------------------------------------------------------
extern "C" void kernel_launch(void* const* d_in, const int* in_sizes, int n_in,
                              void* d_out, int out_size, void* d_ws, size_t ws_size,
                              hipStream_t stream)
{
  #define IN(i) ((const float*)d_in[i])
  const float* img_feat = IN(0);
  const float* option   = IN(1);
  const float* semantic = IN(2);
  const float* queue    = IN(3);
  const float* vae_w1 = IN(4);  const float* vae_b1 = IN(5);
  const float* vae_g1 = IN(6);  const float* vae_be1 = IN(7);
  const float* vae_w2 = IN(8);  const float* vae_b2 = IN(9);
  const float* opt_w1 = IN(10); const float* opt_b1 = IN(11);
  const float* opt_g1 = IN(12); const float* opt_be1 = IN(13);
  const float* opt_w2 = IN(14); const float* opt_b2 = IN(15);
  const float* opt_g2 = IN(16); const float* opt_be2 = IN(17);
  const float* sem_w1 = IN(18); const float* sem_b1 = IN(19);
  const float* sem_g1 = IN(20); const float* sem_be1 = IN(21);
  const float* sem_w2 = IN(22); const float* sem_b2 = IN(23);
  const float* sem_g2 = IN(24); const float* sem_be2 = IN(25);
  const float* fus_w = IN(26);  const float* fus_b = IN(27);
  const float* fus_g = IN(28);  const float* fus_be = IN(29);
  const float* fus_sg = IN(30); const float* fus_sb = IN(31);
  const float* cls_w1 = IN(32); const float* cls_b1 = IN(33);
  const float* cls_g = IN(34);  const float* cls_be = IN(35);
  const float* cls_w2 = IN(36); const float* cls_b2 = IN(37);

  float* ws = (float*)d_ws;
  size_t off = 0;
  auto alloc = [&](size_t n) { float* p = ws + off; off += (n + 255) & ~(size_t)255; return p; };

  const int srows = 128;

  // arena: split-K partials (dense phase) / S stripes + Z4/Z1 (later phases)
  float* arena = alloc(4194304);                 // 16 MB
  float* S  = arena;
  float* Cp = arena;
  float* Z4 = arena;                              // after P-reduce, before kNN
  float* Z1 = arena + 1048576;                    // after head4 partials (at arena[0..1M))
  float* H    = alloc(4 * 1024 * 512);
  float* t1   = alloc(1024 * 512);                // [t1|o1p|s1p] contiguous
  float* o1p  = alloc(1024 * 512);
  float* s1p  = alloc(1024 * 512);
  float* feats = alloc(3 * 1024 * 512);           // [img|optb|semb]
  float* P    = alloc(3 * 1024 * 512);
  // split bf16 transposed weights (alloc counts are floats = u16_count/2)
  u16* vae_w1t = (u16*)alloc(1048576);            // 512x2048 x2
  u16* opt_w1t = (u16*)alloc(393216);             // 512x768 x2
  u16* sem_w1t = (u16*)alloc(393216);
  u16* w2all   = (u16*)alloc(786432);             // 3 x (512x512 x2)
  u16* fusAll  = (u16*)alloc(786432);
  u16* cls_w1t = (u16*)alloc(262144);
  float* qn   = alloc(1024);
  float* kn   = alloc(32768);
  float2* cand = (float2*)alloc(1024 * 64 * 2);
  float* ascL2 = alloc(3*512); float* ashL2 = alloc(3*512);
  float* b2all = alloc(3*512);
  float* sco2 = alloc(512);  float* sho2 = alloc(512);
  float* scs2 = alloc(512);  float* shs2 = alloc(512);
  float* scf  = alloc(4*512); float* shf = alloc(4*512);
  float* scc4 = alloc(4*512); float* shc4 = alloc(4*512);
  float* scc1 = alloc(512);  float* shc1 = alloc(512);
  float* g4   = alloc(4*512); float* b4  = alloc(4*512);
  float* topd2 = alloc(1024 * TK);
  int*   topidx = (int*)alloc(1024 * TK);

  float* fusedb = t1;      // free after L2 batched gemm
  float* neigh  = o1p;     // free after L2 batched gemm

  dim3 blk(256);

  // --- weight transpose+pack (one launch, split hi/lo, padded) ---
  TDs ds;
  ds.d[0] = { vae_w1, vae_w1t, 2048, 2048, 512, 512 };
  ds.d[1] = { opt_w1, opt_w1t,  768,  768, 192, 512 };
  ds.d[2] = { sem_w1, sem_w1t,  768,  768, 192, 512 };
  ds.d[3] = { vae_w2, w2all,              512, 512, 512, 512 };
  ds.d[4] = { opt_w2, w2all + 524288,     192, 512, 512, 512 };
  ds.d[5] = { sem_w2, w2all + 1048576,    192, 512, 512, 512 };
  ds.d[6] = { fus_w,           fusAll,           512, 512, 512, 512 };
  ds.d[7] = { fus_w + 262144,  fusAll + 524288,  512, 512, 512, 512 };
  ds.d[8] = { fus_w + 524288,  fusAll + 1048576, 512, 512, 512, 512 };
  ds.d[9] = { cls_w1, cls_w1t, 512, 512, 512, 512 };
  wt_transpose_kernel<<<dim3(256, 10), blk, 0, stream>>>(ds);

  // --- layer 1: vae1 (z=4), opt1/sem1 (z=3, N padded to 512) ---
  gemm_bt_mfma_kernel<<<dim3(4,16,4), blk, 0, stream>>>(img_feat, vae_w1t, 1048576, 0, nullptr, 0, nullptr, nullptr, 0, Cp, 1024, 512, 2048);
  reduce_bias_kernel<<<dim3(512), blk, 0, stream>>>(Cp, 524288, 4, vae_b1, 512, 0, t1, 512, 131072);
  gemm_bt_mfma_kernel<<<dim3(4,16,3), blk, 0, stream>>>(option, opt_w1t, 393216, 0, nullptr, 0, nullptr, nullptr, 0, Cp, 1024, 512, 768);
  reduce_bias_kernel<<<dim3(512), blk, 0, stream>>>(Cp, 524288, 3, opt_b1, 192, 0, o1p, 512, 131072);
  gemm_bt_mfma_kernel<<<dim3(4,16,3), blk, 0, stream>>>(semantic, sem_w1t, 393216, 0, nullptr, 0, nullptr, nullptr, 0, Cp, 1024, 512, 768);
  reduce_bias_kernel<<<dim3(512), blk, 0, stream>>>(Cp, 524288, 3, sem_b1, 192, 0, s1p, 512, 131072);
  // --- BN stats for layer 2 (into 3-head asc arrays) ---
  bn_stats_kernel<<<dim3(8,1), dim3(1024), 0, stream>>>(t1,  512, vae_g1, vae_be1, 0, 512, ascL2,        ashL2);
  bn_stats_kernel<<<dim3(8,1), dim3(1024), 0, stream>>>(o1p, 512, opt_g1, opt_be1, 0, 192, ascL2 + 512,  ashL2 + 512);
  bn_stats_kernel<<<dim3(8,1), dim3(1024), 0, stream>>>(s1p, 512, sem_g1, sem_be1, 0, 192, ascL2 + 1024, ashL2 + 1024);
  pack3_kernel<<<dim3(6), blk, 0, stream>>>(vae_b2, opt_b2, sem_b2, b2all, 512);
  // --- layer 2 batched (M=3072, BN fused in staging, per-head W/asc), z=2 ---
  gemm_bt_mfma_kernel<<<dim3(4,48,2), blk, 0, stream>>>(t1, w2all, 262144, 524288, nullptr, 0, ascL2, ashL2, 1, Cp, 3072, 512, 512);
  reduce_bias_kernel<<<dim3(1536), blk, 0, stream>>>(Cp, 1572864, 2, b2all, 512, 1, feats, 512, 393216);
  // --- BN+ReLU for optb/semb (in-place; img stays raw) ---
  bn_stats_kernel<<<dim3(8,1), dim3(1024), 0, stream>>>(feats + 524288,  512, opt_g2, opt_be2, 0, 512, sco2, sho2);
  bn_stats_kernel<<<dim3(8,1), dim3(1024), 0, stream>>>(feats + 1048576, 512, sem_g2, sem_be2, 0, 512, scs2, shs2);
  bn_apply512_kernel<<<dim3(512), blk, 0, stream>>>(feats + 524288,  feats + 524288,  sco2, sho2);
  bn_apply512_kernel<<<dim3(512), blk, 0, stream>>>(feats + 1048576, feats + 1048576, scs2, shs2);
  // --- fusion partials batched (M=3072, per-head weights), z=2 ---
  gemm_bt_mfma_kernel<<<dim3(4,48,2), blk, 0, stream>>>(feats, fusAll, 262144, 524288, nullptr, 0, nullptr, nullptr, 1, Cp, 3072, 512, 512);
  reduce_bias_kernel<<<dim3(1536), blk, 0, stream>>>(Cp, 1572864, 2, nullptr, 0, 0, P, 512, 393216);
  fuse_combine_kernel<<<dim3(512), blk, 0, stream>>>(P, fus_w + 1536*512, fus_b, H);
  pack_gb_kernel<<<dim3(8), blk, 0, stream>>>(fus_sg, fus_sb, fus_g, fus_be, g4, b4);
  bn_stats_kernel<<<dim3(8,4), dim3(1024), 0, stream>>>(H, 512, g4, b4, 512, 512, scf, shf);
  bn_apply512_kernel<<<dim3(512), blk, 0, stream>>>(fusedb, H + (size_t)3*1024*512, scf + 1536, shf + 1536);
  // --- classifier heads 0..3 (M=4096, 256 blocks, direct store) ---
  gemm_bt_mfma_kernel<<<dim3(4,64,1), blk, 0, stream>>>(H, cls_w1t, 262144, 0, cls_b1, 512, scf, shf, 1, Z4, 4096, 512, 512);
  bn_stats_kernel<<<dim3(8,4), dim3(1024), 0, stream>>>(Z4, 512, cls_g, cls_be, 0, 512, scc4, shc4);
  gemm_n18_kernel<<<dim3(288), blk, 0, stream>>>(Z4, scc4, shc4, cls_w2, cls_b2, (float*)d_out, 4096);
  // --- kNN retrieval ---
  row_sumsq_kernel<<<dim3(256), blk, 0, stream>>>(fusedb, qn, 1024);
  row_sumsq_kernel<<<dim3(8192), blk, 0, stream>>>(queue, kn, 32768);
  for (int sbase = 0; sbase < 1024; sbase += srows) {
    score_mfma_kernel<<<dim3(256, srows/128), blk, 0, stream>>>(fusedb + (size_t)sbase*512, queue, S);
    topk_scan1_kernel<<<dim3(srows, 4), blk, 0, stream>>>(S, qn, kn, sbase, cand);
  }
  topk_rescue2_kernel<<<dim3(1024), blk, 0, stream>>>(cand, fusedb, queue, qn, kn, topd2, topidx);
  knn_gather_kernel<<<dim3(1024), dim3(64), 0, stream>>>(topd2, topidx, queue, neigh);
  // --- classifier head 4 (z=2 partials into arena, Z1 at arena+1M) ---
  gemm_bt_mfma_kernel<<<dim3(4,16,2), blk, 0, stream>>>(neigh, cls_w1t, 262144, 0, nullptr, 0, nullptr, nullptr, 0, Cp, 1024, 512, 512);
  reduce_bias_kernel<<<dim3(512), blk, 0, stream>>>(Cp, 524288, 2, cls_b1, 512, 0, Z1, 512, 131072);
  bn_stats_kernel<<<dim3(8,1), dim3(1024), 0, stream>>>(Z1, 512, cls_g, cls_be, 0, 512, scc1, shc1);
  gemm_n18_kernel<<<dim3(72), blk, 0, stream>>>(Z1, scc1, shc1, cls_w2, cls_b2, (float*)d_out + 4*1024*18, 1024);
  #undef IN
}

// Round 9
// 719.389 us; speedup vs baseline: 1.7250x; 1.3094x over previous
//
#include <hip/hip_runtime.h>
#include <cstdint>
#include <cstddef>

#define TK 10

typedef unsigned short u16;
typedef __attribute__((ext_vector_type(8))) short short8;
typedef __attribute__((ext_vector_type(4))) float f32x4;

__device__ __forceinline__ float4 ld4(const float* p){ return *(const float4*)p; }

__device__ __forceinline__ u16 bfr(float x){
  unsigned u = __float_as_uint(x);
  return (u16)((u + 0x7FFFu + ((u >> 16) & 1u)) >> 16);
}
__device__ __forceinline__ float b2f(u16 h){
  unsigned u = ((unsigned)h) << 16;
  return __uint_as_float(u);
}

// ---------------------------------------------------------------------------
// wt_transpose: packs weights W[K,N] fp32 -> Wt[Np,Kp] (transposed, padded)
// as SPLIT bf16: hi at [0, Np*Kp), lo at [Np*Kp, 2*Np*Kp).
// ---------------------------------------------------------------------------
struct TD { const float* W; u16* Wt; int K, Kp, N, Np; };
struct TDs { TD d[10]; };

__global__ __launch_bounds__(256) void wt_transpose_kernel(TDs ds)
{
  TD d = ds.d[blockIdx.y];
  const size_t loOff = (size_t)d.Np * d.Kp;
  const int tilesN = d.Np >> 6;
  const int tiles  = (d.Kp >> 6) * tilesN;
  const int tid = blockIdx.x;
  if (tid >= tiles) return;
  const int k0 = (tid / tilesN) << 6, n0 = (tid % tilesN) << 6;
  const int t = threadIdx.x, tc = t & 63, tr = t >> 6;
  __shared__ float L[64][65];
  const bool have = (k0 < d.K) && (n0 < d.N);
  if (have) {
    #pragma unroll
    for (int i = 0; i < 16; ++i) {
      int kk = tr + i * 4;
      L[kk][tc] = d.W[(size_t)(k0 + kk) * d.N + n0 + tc];
    }
  }
  __syncthreads();
  #pragma unroll
  for (int i = 0; i < 16; ++i) {
    int nn = tr + i * 4;
    u16 hi = 0, lo = 0;
    if (have) {
      float v = L[tc][nn];
      hi = bfr(v);
      lo = bfr(v - b2f(hi));
    }
    size_t idx = (size_t)(n0 + nn) * d.Kp + k0 + tc;
    d.Wt[idx] = hi;
    d.Wt[loOff + idx] = lo;
  }
}

// ---------------------------------------------------------------------------
// gemm_bt_mfma v3: split-bf16 3-term, 64x128 tile (MxN), BK=32, double-buffer.
// Per-head (head = m0>>10): weights Bw + head*wstride (lo at +loOff), asc/ash
// at head*K. z>1: plain-store partials to C + z*M*N; z==1: direct + bias.
// ---------------------------------------------------------------------------
__global__ __launch_bounds__(256) void gemm_bt_mfma_kernel(
    const float* __restrict__ A, const u16* __restrict__ Bw,
    size_t loOff, size_t wstride,
    const float* __restrict__ bias, int biasN,
    const float* __restrict__ asc, const float* __restrict__ ash, int headed,
    float* __restrict__ C, int M, int N, int K)
{
  __shared__ u16 AhL[2][64*32], AlL[2][64*32], BhL[2][128*32], BlL[2][128*32];
  const int t  = threadIdx.x;
  const int n0 = blockIdx.x * 128;
  const int m0 = blockIdx.y * 64;
  const int head = headed ? (m0 >> 10) : 0;
  const u16* Bws = Bw + (size_t)head * wstride;
  const int kchunk = K / gridDim.z;
  const int kbeg = blockIdx.z * kchunk;
  const int iters = kchunk >> 5;

  const int aRow = t >> 2, aC = t & 3;
  const int aPhys = (aRow * 4 + (aC ^ (aRow & 3))) * 8;
  const float* gA = A + (size_t)(m0 + aRow) * K + kbeg + aC * 8;
  const int colcA = head * K + kbeg + aC * 8;
  int bPhys[2]; const u16* gBh[2]; const u16* gBl[2];
  #pragma unroll
  for (int i = 0; i < 2; ++i) {
    int L = i * 256 + t;
    int row = L >> 2, c = L & 3;
    bPhys[i] = (row * 4 + (c ^ (row & 3))) * 8;
    gBh[i] = Bws + (size_t)(n0 + row) * K + kbeg + c * 8;
    gBl[i] = gBh[i] + loOff;
  }

  const int lane = t & 63, w = t >> 6;
  const int wm = (w >> 1) * 32, wn = (w & 1) * 64;
  const int q = lane >> 4, rl = lane & 15;

  f32x4 acc[2][4];
  const f32x4 z4 = {0.f, 0.f, 0.f, 0.f};
  #pragma unroll
  for (int i = 0; i < 2; ++i)
    #pragma unroll
    for (int j = 0; j < 4; ++j) acc[i][j] = z4;

  union U16x8 { u16 u[8]; float4 f4; };
  float ra[8]; uint4 rbh[2], rbl[2];

  auto prefetch = [&](int it) {
    const float* pa = gA + it * 32;
    float4 a0 = ld4(pa), a1 = ld4(pa + 4);
    ra[0]=a0.x; ra[1]=a0.y; ra[2]=a0.z; ra[3]=a0.w;
    ra[4]=a1.x; ra[5]=a1.y; ra[6]=a1.z; ra[7]=a1.w;
    #pragma unroll
    for (int i = 0; i < 2; ++i) {
      rbh[i] = *(const uint4*)(gBh[i] + it * 32);
      rbl[i] = *(const uint4*)(gBl[i] + it * 32);
    }
    if (asc) {
      int j0 = colcA + it * 32;
      #pragma unroll
      for (int j = 0; j < 8; ++j)
        ra[j] = fmaxf(0.f, fmaf(ra[j], asc[j0 + j], ash[j0 + j]));
    }
  };
  auto stage = [&](int buf) {
    U16x8 ph, pl;
    #pragma unroll
    for (int j = 0; j < 8; ++j) {
      u16 h = bfr(ra[j]);
      ph.u[j] = h;
      pl.u[j] = bfr(ra[j] - b2f(h));
    }
    *(float4*)&AhL[buf][aPhys] = ph.f4;
    *(float4*)&AlL[buf][aPhys] = pl.f4;
    #pragma unroll
    for (int i = 0; i < 2; ++i) {
      *(uint4*)&BhL[buf][bPhys[i]] = rbh[i];
      *(uint4*)&BlL[buf][bPhys[i]] = rbl[i];
    }
  };
  auto compute = [&](int buf) {
    short8 afh[2], afl[2], bfh[4], bfl[4];
    #pragma unroll
    for (int mt = 0; mt < 2; ++mt) {
      int r = wm + mt * 16 + rl;
      int cc = q ^ (r & 3);
      afh[mt] = *(const short8*)&AhL[buf][(r * 4 + cc) * 8];
      afl[mt] = *(const short8*)&AlL[buf][(r * 4 + cc) * 8];
    }
    #pragma unroll
    for (int nt = 0; nt < 4; ++nt) {
      int r = wn + nt * 16 + rl;
      int cc = q ^ (r & 3);
      bfh[nt] = *(const short8*)&BhL[buf][(r * 4 + cc) * 8];
      bfl[nt] = *(const short8*)&BlL[buf][(r * 4 + cc) * 8];
    }
    #pragma unroll
    for (int mt = 0; mt < 2; ++mt)
      #pragma unroll
      for (int nt = 0; nt < 4; ++nt) {
        acc[mt][nt] = __builtin_amdgcn_mfma_f32_16x16x32_bf16(afl[mt], bfh[nt], acc[mt][nt], 0, 0, 0);
        acc[mt][nt] = __builtin_amdgcn_mfma_f32_16x16x32_bf16(afh[mt], bfl[nt], acc[mt][nt], 0, 0, 0);
        acc[mt][nt] = __builtin_amdgcn_mfma_f32_16x16x32_bf16(afh[mt], bfh[nt], acc[mt][nt], 0, 0, 0);
      }
  };

  prefetch(0);
  stage(0);
  __syncthreads();
  int buf = 0;
  for (int it = 0; it < iters; ++it) {
    if (it + 1 < iters) prefetch(it + 1);
    compute(buf);
    if (it + 1 < iters) { stage(buf ^ 1); __syncthreads(); buf ^= 1; }
  }

  if (gridDim.z == 1) {
    #pragma unroll
    for (int nt = 0; nt < 4; ++nt) {
      int n = n0 + wn + nt * 16 + rl;
      float bv = (bias && n < biasN) ? bias[n] : 0.f;
      #pragma unroll
      for (int mt = 0; mt < 2; ++mt) {
        int m = m0 + wm + mt * 16 + q * 4;
        #pragma unroll
        for (int reg = 0; reg < 4; ++reg)
          C[(size_t)(m + reg) * N + n] = acc[mt][nt][reg] + bv;
      }
    }
  } else {
    float* Cz = C + (size_t)blockIdx.z * M * N;
    #pragma unroll
    for (int nt = 0; nt < 4; ++nt) {
      int n = n0 + wn + nt * 16 + rl;
      #pragma unroll
      for (int mt = 0; mt < 2; ++mt) {
        int m = m0 + wm + mt * 16 + q * 4;
        #pragma unroll
        for (int reg = 0; reg < 4; ++reg)
          Cz[(size_t)(m + reg) * N + n] = acc[mt][nt][reg];
      }
    }
  }
}

// C[i] = sum_z Cp[z][i] + bias; headedBias: bias idx = (row>>10)*N + col.
__global__ void reduce_bias_kernel(const float* __restrict__ Cp, size_t slice, int z,
    const float* __restrict__ bias, int biasN, int headedBias,
    float* __restrict__ C, int N, int total4)
{
  int i = blockIdx.x * 256 + threadIdx.x;
  if (i >= total4) return;
  size_t base = (size_t)i * 4;
  float4 s = ld4(Cp + base);
  for (int zz = 1; zz < z; ++zz) {
    float4 v = ld4(Cp + (size_t)zz * slice + base);
    s.x += v.x; s.y += v.y; s.z += v.z; s.w += v.w;
  }
  if (bias) {
    int col = (int)(base % (size_t)N);
    int boff = headedBias ? (int)(base / ((size_t)1024 * N)) * N : 0;
    if (col + 0 < biasN) s.x += bias[boff + col + 0];
    if (col + 1 < biasN) s.y += bias[boff + col + 1];
    if (col + 2 < biasN) s.z += bias[boff + col + 2];
    if (col + 3 < biasN) s.w += bias[boff + col + 3];
  }
  *(float4*)&C[base] = s;
}

__global__ void pack3_kernel(const float* __restrict__ a, const float* __restrict__ b,
    const float* __restrict__ c, float* __restrict__ dst, int n)
{
  int i = blockIdx.x * 256 + threadIdx.x;
  if (i < n) dst[i] = a[i];
  else if (i < 2*n) dst[i] = b[i - n];
  else if (i < 3*n) dst[i] = c[i - 2*n];
}

// ---------------------------------------------------------------------------
// score_mfma: approx scores, single bf16 (selection only; rescue is exact).
// ---------------------------------------------------------------------------
__global__ __launch_bounds__(256) void score_mfma_kernel(
    const float* __restrict__ A, const float* __restrict__ Bq,
    float* __restrict__ C)
{
  __shared__ u16 At[128 * 64];
  __shared__ u16 Bt[128 * 64];
  const int t  = threadIdx.x;
  const int n0 = blockIdx.x * 128;
  const int m0 = blockIdx.y * 128;

  u16* ldsA[4]; u16* ldsB[4];
  const float* gA[4]; const float* gB[4];
  #pragma unroll
  for (int i = 0; i < 4; ++i) {
    int L = i * 256 + t;
    int row = L >> 3, c = L & 7;
    int phys = row * 8 + (c ^ (row & 7));
    ldsA[i] = &At[phys * 8]; ldsB[i] = &Bt[phys * 8];
    gA[i] = A  + (size_t)(m0 + row) * 512 + c * 8;
    gB[i] = Bq + (size_t)(n0 + row) * 512 + c * 8;
  }

  const int lane = t & 63, w = t >> 6;
  const int wm = (w >> 1) * 64, wn = (w & 1) * 64;
  const int q = lane >> 4, rl = lane & 15;

  f32x4 acc[4][4];
  const f32x4 z4 = {0.f, 0.f, 0.f, 0.f};
  #pragma unroll
  for (int i = 0; i < 4; ++i)
    #pragma unroll
    for (int j = 0; j < 4; ++j) acc[i][j] = z4;

  union U16x8 { u16 u[8]; float4 f4; };

  for (int k0 = 0; k0 < 512; k0 += 64) {
    float4 ra[4][2], rb[4][2];
    #pragma unroll
    for (int i = 0; i < 4; ++i) {
      ra[i][0] = ld4(gA[i]); ra[i][1] = ld4(gA[i] + 4);
      rb[i][0] = ld4(gB[i]); rb[i][1] = ld4(gB[i] + 4);
      gA[i] += 64; gB[i] += 64;
    }
    __syncthreads();
    #pragma unroll
    for (int i = 0; i < 4; ++i) {
      U16x8 pa, pb;
      pa.u[0]=bfr(ra[i][0].x); pa.u[1]=bfr(ra[i][0].y); pa.u[2]=bfr(ra[i][0].z); pa.u[3]=bfr(ra[i][0].w);
      pa.u[4]=bfr(ra[i][1].x); pa.u[5]=bfr(ra[i][1].y); pa.u[6]=bfr(ra[i][1].z); pa.u[7]=bfr(ra[i][1].w);
      pb.u[0]=bfr(rb[i][0].x); pb.u[1]=bfr(rb[i][0].y); pb.u[2]=bfr(rb[i][0].z); pb.u[3]=bfr(rb[i][0].w);
      pb.u[4]=bfr(rb[i][1].x); pb.u[5]=bfr(rb[i][1].y); pb.u[6]=bfr(rb[i][1].z); pb.u[7]=bfr(rb[i][1].w);
      *(float4*)ldsA[i] = pa.f4;
      *(float4*)ldsB[i] = pb.f4;
    }
    __syncthreads();
    #pragma unroll
    for (int kk = 0; kk < 2; ++kk) {
      short8 af[4], bfv[4];
      #pragma unroll
      for (int mt = 0; mt < 4; ++mt) {
        int r = wm + mt * 16 + rl;
        int cc = (kk * 4 + q) ^ (r & 7);
        af[mt] = *(const short8*)&At[(r * 8 + cc) * 8];
      }
      #pragma unroll
      for (int nt = 0; nt < 4; ++nt) {
        int r = wn + nt * 16 + rl;
        int cc = (kk * 4 + q) ^ (r & 7);
        bfv[nt] = *(const short8*)&Bt[(r * 8 + cc) * 8];
      }
      #pragma unroll
      for (int mt = 0; mt < 4; ++mt)
        #pragma unroll
        for (int nt = 0; nt < 4; ++nt)
          acc[mt][nt] = __builtin_amdgcn_mfma_f32_16x16x32_bf16(af[mt], bfv[nt], acc[mt][nt], 0, 0, 0);
    }
  }
  #pragma unroll
  for (int mt = 0; mt < 4; ++mt)
    #pragma unroll
    for (int nt = 0; nt < 4; ++nt) {
      int m = m0 + wm + mt * 16 + q * 4;
      int n = n0 + wn + nt * 16 + rl;
      #pragma unroll
      for (int reg = 0; reg < 4; ++reg)
        C[(size_t)(m + reg) * 32768 + n] = acc[mt][nt][reg];
    }
}

// ---------------------------------------------------------------------------
// BN column stats over 1024 rows -> scale/shift.
// ---------------------------------------------------------------------------
__global__ __launch_bounds__(1024) void bn_stats_kernel(const float* __restrict__ X, int N,
    const float* __restrict__ gamma, const float* __restrict__ beta, int gstride, int gN,
    float* __restrict__ scale, float* __restrict__ shift)
{
  const int head = blockIdx.y;
  const float* Xh = X + (size_t)head * 1024 * N;
  const int lane = threadIdx.x & 63;
  const int col  = blockIdx.x * 64 + lane;
  const int rg   = threadIdx.x >> 6;
  float s = 0.f, ss = 0.f;
  const float* p = Xh + (size_t)(rg * 64) * N + col;
  for (int rr = 0; rr < 64; ++rr) { float v = *p; p += N; s += v; ss = fmaf(v, v, ss); }
  __shared__ float Ssum[16][64], Ssq[16][64];
  Ssum[rg][lane] = s; Ssq[rg][lane] = ss;
  __syncthreads();
  if (threadIdx.x < 64) {
    s = 0.f; ss = 0.f;
    #pragma unroll
    for (int r = 0; r < 16; ++r) { s += Ssum[r][lane]; ss += Ssq[r][lane]; }
    float mean = s * (1.f / 1024.f);
    float var  = ss * (1.f / 1024.f) - mean * mean;
    float sc = 0.f, sh = 0.f;
    if (col < gN) {
      sc = gamma[head * gstride + col] / sqrtf(var + 1e-5f);
      sh = beta[head * gstride + col] - mean * sc;
    }
    scale[head * N + col] = sc;
    shift[head * N + col] = sh;
  }
}

__global__ void bn_apply512_kernel(float* __restrict__ dst, const float* __restrict__ src,
    const float* __restrict__ scale, const float* __restrict__ shift)
{
  int i = blockIdx.x * 256 + threadIdx.x;
  if (i >= 131072) return;
  size_t base = (size_t)i * 4;
  int col = (int)(base & 511);
  float4 v = ld4(src + base);
  v.x = fmaxf(0.f, fmaf(v.x, scale[col+0], shift[col+0]));
  v.y = fmaxf(0.f, fmaf(v.y, scale[col+1], shift[col+1]));
  v.z = fmaxf(0.f, fmaf(v.z, scale[col+2], shift[col+2]));
  v.w = fmaxf(0.f, fmaf(v.w, scale[col+3], shift[col+3]));
  *(float4*)&dst[base] = v;
}

__global__ void fuse_combine_kernel(const float* __restrict__ P,
    const float* __restrict__ fwr, const float* __restrict__ fb, float* __restrict__ H)
{
  int i = blockIdx.x * 256 + threadIdx.x;
  if (i >= 131072) return;
  size_t base = (size_t)i * 4;
  int c = (int)(base & 511);
  float4 p0 = ld4(P + base), p1 = ld4(P + 524288 + base), p2 = ld4(P + 1048576 + base);
  float4 w0 = ld4(fwr + c), w1 = ld4(fwr + 512 + c), w2 = ld4(fwr + 1024 + c), b = ld4(fb + c);
  float4 h0, h1, h2, h3;
  h0.x=p0.x+w0.x+b.x; h0.y=p0.y+w0.y+b.y; h0.z=p0.z+w0.z+b.z; h0.w=p0.w+w0.w+b.w;
  h1.x=p1.x+w1.x+b.x; h1.y=p1.y+w1.y+b.y; h1.z=p1.z+w1.z+b.z; h1.w=p1.w+w1.w+b.w;
  h2.x=p2.x+w2.x+b.x; h2.y=p2.y+w2.y+b.y; h2.z=p2.z+w2.z+b.z; h2.w=p2.w+w2.w+b.w;
  h3.x=p0.x+p1.x+p2.x+w0.x+w1.x+w2.x+b.x;
  h3.y=p0.y+p1.y+p2.y+w0.y+w1.y+w2.y+b.y;
  h3.z=p0.z+p1.z+p2.z+w0.z+w1.z+w2.z+b.z;
  h3.w=p0.w+p1.w+p2.w+w0.w+w1.w+w2.w+b.w;
  *(float4*)&H[base]           = h0;
  *(float4*)&H[524288 + base]  = h1;
  *(float4*)&H[1048576 + base] = h2;
  *(float4*)&H[1572864 + base] = h3;
}

__global__ void pack_gb_kernel(const float* __restrict__ sg, const float* __restrict__ sb,
    const float* __restrict__ g, const float* __restrict__ be,
    float* __restrict__ g4, float* __restrict__ b4)
{
  int i = blockIdx.x * 256 + threadIdx.x;
  if (i < 1536)      { g4[i] = sg[i];      b4[i] = sb[i]; }
  else if (i < 2048) { g4[i] = g[i-1536];  b4[i] = be[i-1536]; }
}

__global__ void row_sumsq_kernel(const float* __restrict__ X, float* __restrict__ out, int nrows)
{
  int row  = blockIdx.x * 4 + (threadIdx.x >> 6);
  int lane = threadIdx.x & 63;
  if (row >= nrows) return;
  const float* p = X + (size_t)row * 512 + lane * 8;
  float4 a = ld4(p), b = ld4(p + 4);
  float s = a.x*a.x + a.y*a.y + a.z*a.z + a.w*a.w
          + b.x*b.x + b.y*b.y + b.z*b.z + b.w*b.w;
  for (int off = 32; off; off >>= 1) s += __shfl_down(s, off, 64);
  if (lane == 0) out[row] = s;
}

// ---------------------------------------------------------------------------
// topk_scan1 / topk_rescue2 / knn_gather — unchanged (R3-verified).
// ---------------------------------------------------------------------------
__global__ __launch_bounds__(256) void topk_scan1_kernel(const float* __restrict__ S,
    const float* __restrict__ qn, const float* __restrict__ kn, int rowbase,
    float2* __restrict__ cand)
{
  const int row  = blockIdx.x;
  const int grow = rowbase + row;
  const int cb   = blockIdx.y;
  const float qnr = qn[grow];
  const float* Srow = S + (size_t)row * 32768 + cb * 8192;
  const float* knb  = kn + cb * 8192;
  const int t = threadIdx.x;
  const float INF = __builtin_inff();

  float vals[6]; int idxs[6];
  #pragma unroll
  for (int j = 0; j < 6; ++j) { vals[j] = INF; idxs[j] = 0x7fffffff; }

  auto ins = [&](float d2, int ci) {
    if (d2 < vals[5] || (d2 == vals[5] && ci < idxs[5])) {
      float cv = d2; int cc = ci;
      #pragma unroll
      for (int j = 0; j < 6; ++j) {
        bool less = (cv < vals[j]) || (cv == vals[j] && cc < idxs[j]);
        float tv = less ? vals[j] : cv; int ti = less ? idxs[j] : cc;
        vals[j] = less ? cv : vals[j]; idxs[j] = less ? cc : idxs[j];
        cv = tv; cc = ti;
      }
    }
  };

  #pragma unroll
  for (int i = 0; i < 8; ++i) {
    int c = (i * 256 + t) * 4;
    float4 s4 = ld4(Srow + c);
    float4 k4 = ld4(knb + c);
    int gcol = cb * 8192 + c;
    ins((qnr + k4.x) - 2.f * s4.x, gcol + 0);
    ins((qnr + k4.y) - 2.f * s4.y, gcol + 1);
    ins((qnr + k4.z) - 2.f * s4.z, gcol + 2);
    ins((qnr + k4.w) - 2.f * s4.w, gcol + 3);
  }

  __shared__ float Wv[4]; __shared__ int Wi[4];
  const int lane = t & 63, wid = t >> 6;
  for (int sel = 0; sel < 16; ++sel) {
    float bv = vals[0]; int bi = idxs[0];
    #pragma unroll
    for (int off = 32; off >= 1; off >>= 1) {
      float ov = __shfl_down(bv, off, 64);
      int   oi = __shfl_down(bi, off, 64);
      if (ov < bv || (ov == bv && oi < bi)) { bv = ov; bi = oi; }
    }
    if (lane == 0) { Wv[wid] = bv; Wi[wid] = bi; }
    __syncthreads();
    float gv = Wv[0]; int gi = Wi[0];
    #pragma unroll
    for (int w2 = 1; w2 < 4; ++w2) {
      float wv2 = Wv[w2]; int wi2 = Wi[w2];
      if (wv2 < gv || (wv2 == gv && wi2 < gi)) { gv = wv2; gi = wi2; }
    }
    if (t == 0) {
      float2 e; e.x = gv; e.y = __int_as_float(gi);
      cand[(size_t)grow * 64 + cb * 16 + sel] = e;
    }
    if (vals[0] == gv && idxs[0] == gi) {
      #pragma unroll
      for (int j = 0; j < 5; ++j) { vals[j] = vals[j+1]; idxs[j] = idxs[j+1]; }
      vals[5] = INF; idxs[5] = 0x7fffffff;
    }
    __syncthreads();
  }
}

__global__ __launch_bounds__(256) void topk_rescue2_kernel(const float2* __restrict__ cand,
    const float* __restrict__ fusedF, const float* __restrict__ queue,
    const float* __restrict__ qn, const float* __restrict__ kn,
    float* __restrict__ topd2, int* __restrict__ topidx)
{
  const int grow = blockIdx.x;
  const int t = threadIdx.x;
  const float INF = __builtin_inff();
  const float qnr = qn[grow];
  __shared__ int Ci[16]; __shared__ float Cd[16];

  if (t < 64) {
    float2 e = cand[(size_t)grow * 64 + t];
    float v = e.x; int id = __float_as_int(e.y);
    for (int sel = 0; sel < 16; ++sel) {
      float bv = v; int bi = id;
      #pragma unroll
      for (int off = 32; off >= 1; off >>= 1) {
        float ov = __shfl_down(bv, off, 64);
        int   oi = __shfl_down(bi, off, 64);
        if (ov < bv || (ov == bv && oi < bi)) { bv = ov; bi = oi; }
      }
      bv = __shfl(bv, 0, 64); bi = __shfl(bi, 0, 64);
      if (t == 0) Ci[sel] = bi;
      if (id == bi) { v = INF; id = 0x7fffffff; }
    }
  }
  __syncthreads();

  {
    int c = t >> 4, s = t & 15;
    int qi = Ci[c];
    const float* qp = queue  + (size_t)qi * 512 + s * 32;
    const float* fp = fusedF + (size_t)grow * 512 + s * 32;
    float dot = 0.f;
    #pragma unroll
    for (int j = 0; j < 8; ++j) {
      float4 a = ld4(fp + j*4); float4 b = ld4(qp + j*4);
      dot += a.x*b.x + a.y*b.y + a.z*b.z + a.w*b.w;
    }
    #pragma unroll
    for (int off = 8; off >= 1; off >>= 1) dot += __shfl_down(dot, off, 16);
    if (s == 0) Cd[c] = qnr + kn[qi] - 2.f * dot;
  }
  __syncthreads();

  if (t < 64) {
    float v = (t < 16) ? Cd[t] : INF;
    int  id = (t < 16) ? Ci[t] : 0x7fffffff;
    for (int sel = 0; sel < TK; ++sel) {
      float bv = v; int bi = id;
      #pragma unroll
      for (int off = 32; off >= 1; off >>= 1) {
        float ov = __shfl_down(bv, off, 64);
        int   oi = __shfl_down(bi, off, 64);
        if (ov < bv || (ov == bv && oi < bi)) { bv = ov; bi = oi; }
      }
      bv = __shfl(bv, 0, 64); bi = __shfl(bi, 0, 64);
      if (t == 0) { topd2[grow*TK + sel] = bv; topidx[grow*TK + sel] = bi; }
      if (id == bi) { v = INF; id = 0x7fffffff; }
    }
  }
}

__global__ void knn_gather_kernel(const float* __restrict__ topd2, const int* __restrict__ topidx,
    const float* __restrict__ queue, float* __restrict__ neigh)
{
  const int row = blockIdx.x;
  const int t = threadIdx.x;   // 64
  __shared__ float ls[TK]; __shared__ float wv[TK]; __shared__ int wid[TK];
  if (t < TK) {
    float d = sqrtf(fmaxf(topd2[row*TK + t], 0.f));
    ls[t]  = -d / 0.07f;
    wid[t] = topidx[row*TK + t];
  }
  __syncthreads();
  if (t < TK) {
    float m = ls[0];
    #pragma unroll
    for (int j = 1; j < TK; ++j) m = fmaxf(m, ls[j]);
    wv[t] = __expf(ls[t] - m);
  }
  __syncthreads();
  float ssum = 0.f;
  #pragma unroll
  for (int j = 0; j < TK; ++j) ssum += wv[j];
  float inv = 1.f / ssum;
  #pragma unroll
  for (int u = 0; u < 8; ++u) {
    int c = u * 64 + t;
    float acc = 0.f;
    #pragma unroll
    for (int k = 0; k < TK; ++k)
      acc = fmaf(wv[k] * inv, queue[(size_t)wid[k] * 512 + c], acc);
    neigh[(size_t)row * 512 + c] = acc;
  }
}

// ---------------------------------------------------------------------------
// gemm_n18 v2: out[r,c] = b2[c] + sum_k relu(Z[r,k]*sc+sh) * W2[k,c].
// Block = 16 rows x 16 k-slices. W2 in LDS (stride 19: 2-way bank alias,
// free). Coalesced float4 Z loads, 18 reg accumulators, 16-wide shfl reduce.
// Grid = Mrows/16; all rows of a block share one head (16 | 1024).
// ---------------------------------------------------------------------------
__global__ __launch_bounds__(256) void gemm_n18_kernel(const float* __restrict__ Z,
    const float* __restrict__ sc, const float* __restrict__ sh,
    const float* __restrict__ W2, const float* __restrict__ b2,
    float* __restrict__ out)
{
  __shared__ float W2s[512 * 19];
  __shared__ float scs[512], shs[512];
  const int t = threadIdx.x;
  const int rowBase = blockIdx.x * 16;
  const int head = rowBase >> 10;
  for (int i = t; i < 9216; i += 256) {
    int k = i / 18, c = i - k * 18;
    W2s[k * 19 + c] = W2[i];
  }
  for (int i = t; i < 512; i += 256) {
    scs[i] = sc[head * 512 + i];
    shs[i] = sh[head * 512 + i];
  }
  __syncthreads();
  const int ry = t >> 4, s = t & 15;
  const int row = rowBase + ry;
  const float* zp = Z + (size_t)row * 512;
  float acc[18];
  #pragma unroll
  for (int c = 0; c < 18; ++c) acc[c] = 0.f;
  #pragma unroll
  for (int j = 0; j < 8; ++j) {
    int k = j * 64 + s * 4;
    float4 z = ld4(zp + k);
    float4 a = ld4(scs + k);
    float4 b = ld4(shs + k);
    float z0 = fmaxf(0.f, fmaf(z.x, a.x, b.x));
    float z1 = fmaxf(0.f, fmaf(z.y, a.y, b.y));
    float z2 = fmaxf(0.f, fmaf(z.z, a.z, b.z));
    float z3 = fmaxf(0.f, fmaf(z.w, a.w, b.w));
    const float* w0 = &W2s[(k + 0) * 19];
    const float* w1 = &W2s[(k + 1) * 19];
    const float* w2 = &W2s[(k + 2) * 19];
    const float* w3 = &W2s[(k + 3) * 19];
    #pragma unroll
    for (int c = 0; c < 18; ++c) {
      float v = fmaf(z0, w0[c], fmaf(z1, w1[c], fmaf(z2, w2[c], z3 * w3[c])));
      acc[c] += v;
    }
  }
  #pragma unroll
  for (int c = 0; c < 18; ++c) {
    acc[c] += __shfl_down(acc[c], 8, 16);
    acc[c] += __shfl_down(acc[c], 4, 16);
    acc[c] += __shfl_down(acc[c], 2, 16);
    acc[c] += __shfl_down(acc[c], 1, 16);
  }
  if (s == 0) {
    #pragma unroll
    for (int c = 0; c < 18; ++c) out[row * 18 + c] = acc[c] + b2[c];
  }
}

// ---------------------------------------------------------------------------
extern "C" void kernel_launch(void* const* d_in, const int* in_sizes, int n_in,
                              void* d_out, int out_size, void* d_ws, size_t ws_size,
                              hipStream_t stream)
{
  #define IN(i) ((const float*)d_in[i])
  const float* img_feat = IN(0);
  const float* option   = IN(1);
  const float* semantic = IN(2);
  const float* queue    = IN(3);
  const float* vae_w1 = IN(4);  const float* vae_b1 = IN(5);
  const float* vae_g1 = IN(6);  const float* vae_be1 = IN(7);
  const float* vae_w2 = IN(8);  const float* vae_b2 = IN(9);
  const float* opt_w1 = IN(10); const float* opt_b1 = IN(11);
  const float* opt_g1 = IN(12); const float* opt_be1 = IN(13);
  const float* opt_w2 = IN(14); const float* opt_b2 = IN(15);
  const float* opt_g2 = IN(16); const float* opt_be2 = IN(17);
  const float* sem_w1 = IN(18); const float* sem_b1 = IN(19);
  const float* sem_g1 = IN(20); const float* sem_be1 = IN(21);
  const float* sem_w2 = IN(22); const float* sem_b2 = IN(23);
  const float* sem_g2 = IN(24); const float* sem_be2 = IN(25);
  const float* fus_w = IN(26);  const float* fus_b = IN(27);
  const float* fus_g = IN(28);  const float* fus_be = IN(29);
  const float* fus_sg = IN(30); const float* fus_sb = IN(31);
  const float* cls_w1 = IN(32); const float* cls_b1 = IN(33);
  const float* cls_g = IN(34);  const float* cls_be = IN(35);
  const float* cls_w2 = IN(36); const float* cls_b2 = IN(37);

  float* ws = (float*)d_ws;
  size_t off = 0;
  auto alloc = [&](size_t n) { float* p = ws + off; off += (n + 255) & ~(size_t)255; return p; };

  const int srows = (ws_size >= (size_t)78 * 1024 * 1024) ? 256 : 128;

  // arena: split-K partials (dense phase) / S stripes + Z4/Z1 (later phases)
  float* arena = alloc((size_t)srows * 32768);
  float* S  = arena;
  float* Cp = arena;
  float* Z4 = arena;
  float* Z1 = arena + 2097152;           // after head4 partials (arena[0..1M))
  float* H    = alloc(4 * 1024 * 512);
  float* t1   = alloc(1024 * 512);       // [t1|o1p|s1p] contiguous
  float* o1p  = alloc(1024 * 512);
  float* s1p  = alloc(1024 * 512);
  float* feats = alloc(3 * 1024 * 512);  // [img|optb|semb]
  float* P    = alloc(3 * 1024 * 512);
  u16* vae_w1t = (u16*)alloc(1048576);
  u16* opt_w1t = (u16*)alloc(393216);
  u16* sem_w1t = (u16*)alloc(393216);
  u16* w2all   = (u16*)alloc(786432);
  u16* fusAll  = (u16*)alloc(786432);
  u16* cls_w1t = (u16*)alloc(262144);
  float* qn   = alloc(1024);
  float* kn   = alloc(32768);
  float2* cand = (float2*)alloc(1024 * 64 * 2);
  float* ascL2 = alloc(3*512); float* ashL2 = alloc(3*512);
  float* b2all = alloc(3*512);
  float* sco2 = alloc(512);  float* sho2 = alloc(512);
  float* scs2 = alloc(512);  float* shs2 = alloc(512);
  float* scf  = alloc(4*512); float* shf = alloc(4*512);
  float* scc4 = alloc(4*512); float* shc4 = alloc(4*512);
  float* scc1 = alloc(512);  float* shc1 = alloc(512);
  float* g4   = alloc(4*512); float* b4  = alloc(4*512);
  float* topd2 = alloc(1024 * TK);
  int*   topidx = (int*)alloc(1024 * TK);

  float* fusedb = t1;
  float* neigh  = o1p;

  dim3 blk(256);

  TDs ds;
  ds.d[0] = { vae_w1, vae_w1t, 2048, 2048, 512, 512 };
  ds.d[1] = { opt_w1, opt_w1t,  768,  768, 192, 512 };
  ds.d[2] = { sem_w1, sem_w1t,  768,  768, 192, 512 };
  ds.d[3] = { vae_w2, w2all,              512, 512, 512, 512 };
  ds.d[4] = { opt_w2, w2all + 524288,     192, 512, 512, 512 };
  ds.d[5] = { sem_w2, w2all + 1048576,    192, 512, 512, 512 };
  ds.d[6] = { fus_w,           fusAll,           512, 512, 512, 512 };
  ds.d[7] = { fus_w + 262144,  fusAll + 524288,  512, 512, 512, 512 };
  ds.d[8] = { fus_w + 524288,  fusAll + 1048576, 512, 512, 512, 512 };
  ds.d[9] = { cls_w1, cls_w1t, 512, 512, 512, 512 };
  wt_transpose_kernel<<<dim3(256, 10), blk, 0, stream>>>(ds);

  // --- layer 1 ---
  gemm_bt_mfma_kernel<<<dim3(4,16,4), blk, 0, stream>>>(img_feat, vae_w1t, 1048576, 0, nullptr, 0, nullptr, nullptr, 0, Cp, 1024, 512, 2048);
  reduce_bias_kernel<<<dim3(512), blk, 0, stream>>>(Cp, 524288, 4, vae_b1, 512, 0, t1, 512, 131072);
  gemm_bt_mfma_kernel<<<dim3(4,16,3), blk, 0, stream>>>(option, opt_w1t, 393216, 0, nullptr, 0, nullptr, nullptr, 0, Cp, 1024, 512, 768);
  reduce_bias_kernel<<<dim3(512), blk, 0, stream>>>(Cp, 524288, 3, opt_b1, 192, 0, o1p, 512, 131072);
  gemm_bt_mfma_kernel<<<dim3(4,16,3), blk, 0, stream>>>(semantic, sem_w1t, 393216, 0, nullptr, 0, nullptr, nullptr, 0, Cp, 1024, 512, 768);
  reduce_bias_kernel<<<dim3(512), blk, 0, stream>>>(Cp, 524288, 3, sem_b1, 192, 0, s1p, 512, 131072);
  // --- BN stats for layer 2 ---
  bn_stats_kernel<<<dim3(8,1), dim3(1024), 0, stream>>>(t1,  512, vae_g1, vae_be1, 0, 512, ascL2,        ashL2);
  bn_stats_kernel<<<dim3(8,1), dim3(1024), 0, stream>>>(o1p, 512, opt_g1, opt_be1, 0, 192, ascL2 + 512,  ashL2 + 512);
  bn_stats_kernel<<<dim3(8,1), dim3(1024), 0, stream>>>(s1p, 512, sem_g1, sem_be1, 0, 192, ascL2 + 1024, ashL2 + 1024);
  pack3_kernel<<<dim3(6), blk, 0, stream>>>(vae_b2, opt_b2, sem_b2, b2all, 512);
  // --- layer 2 batched ---
  gemm_bt_mfma_kernel<<<dim3(4,48,2), blk, 0, stream>>>(t1, w2all, 262144, 524288, nullptr, 0, ascL2, ashL2, 1, Cp, 3072, 512, 512);
  reduce_bias_kernel<<<dim3(1536), blk, 0, stream>>>(Cp, 1572864, 2, b2all, 512, 1, feats, 512, 393216);
  bn_stats_kernel<<<dim3(8,1), dim3(1024), 0, stream>>>(feats + 524288,  512, opt_g2, opt_be2, 0, 512, sco2, sho2);
  bn_stats_kernel<<<dim3(8,1), dim3(1024), 0, stream>>>(feats + 1048576, 512, sem_g2, sem_be2, 0, 512, scs2, shs2);
  bn_apply512_kernel<<<dim3(512), blk, 0, stream>>>(feats + 524288,  feats + 524288,  sco2, sho2);
  bn_apply512_kernel<<<dim3(512), blk, 0, stream>>>(feats + 1048576, feats + 1048576, scs2, shs2);
  // --- fusion partials batched ---
  gemm_bt_mfma_kernel<<<dim3(4,48,2), blk, 0, stream>>>(feats, fusAll, 262144, 524288, nullptr, 0, nullptr, nullptr, 1, Cp, 3072, 512, 512);
  reduce_bias_kernel<<<dim3(1536), blk, 0, stream>>>(Cp, 1572864, 2, nullptr, 0, 0, P, 512, 393216);
  fuse_combine_kernel<<<dim3(512), blk, 0, stream>>>(P, fus_w + 1536*512, fus_b, H);
  pack_gb_kernel<<<dim3(8), blk, 0, stream>>>(fus_sg, fus_sb, fus_g, fus_be, g4, b4);
  bn_stats_kernel<<<dim3(8,4), dim3(1024), 0, stream>>>(H, 512, g4, b4, 512, 512, scf, shf);
  bn_apply512_kernel<<<dim3(512), blk, 0, stream>>>(fusedb, H + (size_t)3*1024*512, scf + 1536, shf + 1536);
  // --- classifier heads 0..3 ---
  gemm_bt_mfma_kernel<<<dim3(4,64,1), blk, 0, stream>>>(H, cls_w1t, 262144, 0, cls_b1, 512, scf, shf, 1, Z4, 4096, 512, 512);
  bn_stats_kernel<<<dim3(8,4), dim3(1024), 0, stream>>>(Z4, 512, cls_g, cls_be, 0, 512, scc4, shc4);
  gemm_n18_kernel<<<dim3(256), blk, 0, stream>>>(Z4, scc4, shc4, cls_w2, cls_b2, (float*)d_out);
  // --- kNN retrieval ---
  row_sumsq_kernel<<<dim3(256), blk, 0, stream>>>(fusedb, qn, 1024);
  row_sumsq_kernel<<<dim3(8192), blk, 0, stream>>>(queue, kn, 32768);
  for (int sbase = 0; sbase < 1024; sbase += srows) {
    score_mfma_kernel<<<dim3(256, srows/128), blk, 0, stream>>>(fusedb + (size_t)sbase*512, queue, S);
    topk_scan1_kernel<<<dim3(srows, 4), blk, 0, stream>>>(S, qn, kn, sbase, cand);
  }
  topk_rescue2_kernel<<<dim3(1024), blk, 0, stream>>>(cand, fusedb, queue, qn, kn, topd2, topidx);
  knn_gather_kernel<<<dim3(1024), dim3(64), 0, stream>>>(topd2, topidx, queue, neigh);
  // --- classifier head 4 (z=2 partials at arena[0..1M), Z1 at arena+2M) ---
  gemm_bt_mfma_kernel<<<dim3(4,16,2), blk, 0, stream>>>(neigh, cls_w1t, 262144, 0, nullptr, 0, nullptr, nullptr, 0, Cp, 1024, 512, 512);
  reduce_bias_kernel<<<dim3(512), blk, 0, stream>>>(Cp, 524288, 2, cls_b1, 512, 0, Z1, 512, 131072);
  bn_stats_kernel<<<dim3(8,1), dim3(1024), 0, stream>>>(Z1, 512, cls_g, cls_be, 0, 512, scc1, shc1);
  gemm_n18_kernel<<<dim3(64), blk, 0, stream>>>(Z1, scc1, shc1, cls_w2, cls_b2, (float*)d_out + 4*1024*18);
  #undef IN
}